// Round 5
// baseline (477.647 us; speedup 1.0000x reference)
//
#include <hip/hip_runtime.h>
#include <hip/hip_bf16.h>
#include <math.h>

typedef __hip_bfloat16 bf16;
typedef __bf16 bf16x8 __attribute__((ext_vector_type(8)));
typedef float  f32x4  __attribute__((ext_vector_type(4)));

#define DEVI __device__ __forceinline__

static constexpr int Bb     = 2;
static constexpr int Ss     = 2048;
static constexpr int DMODEL = 1024;
static constexpr int NTOK   = Bb * Ss;   // 4096

DEVI float bf2f(bf16 v) { return __bfloat162float(v); }
DEVI bf16  f2bf(float v) { return __float2bfloat16(v); }

DEVI unsigned int packbf(float lo, float hi) {
  union { bf16 b; unsigned short u; } a, c;
  a.b = f2bf(lo); c.b = f2bf(hi);
  return ((unsigned int)c.u << 16) | a.u;
}

DEVI void async_load16(const bf16* g, bf16* l) {
  __builtin_amdgcn_global_load_lds((const __attribute__((address_space(1))) void*)g,
                                   (__attribute__((address_space(3))) void*)l, 16, 0, 0);
}

// ---------------------------------------------------------------- fp32 -> bf16 convert
__global__ __launch_bounds__(256) void convert_kernel(
    const float* __restrict__ in, bf16* __restrict__ out, int n4) {
  const int t = blockIdx.x * blockDim.x + threadIdx.x;
  if (t >= n4) return;
  const float4 v = ((const float4*)in)[t];
  bf16 o[4] = { f2bf(v.x), f2bf(v.y), f2bf(v.z), f2bf(v.w) };
  *(ushort4*)&out[(size_t)t * 4] = *(const ushort4*)o;
}

// ---------------------------------------------------------------- fused weight transpose
// out[c][r] = bf16(in[r][c]) for 8 fp32 matrices in one dispatch
struct TransDesc { const float* src; bf16* dst; int R; int C; int tstart; };
struct TransPack { TransDesc d[8]; };

__global__ __launch_bounds__(256) void transpose8_kernel(TransPack p) {
  const int t = blockIdx.x;
  int i = 0;
#pragma unroll
  for (int j = 1; j < 8; ++j) if (t >= p.d[j].tstart) i = j;
  const float* __restrict__ in = p.d[i].src;
  bf16* __restrict__ out = p.d[i].dst;
  const int R = p.d[i].R, C = p.d[i].C;
  const int rel = t - p.d[i].tstart;
  const int tilesC = C >> 6;
  const int r0 = (rel / tilesC) * 64, c0 = (rel % tilesC) * 64;

  __shared__ bf16 tl[64][65];
  const int tc = threadIdx.x & 63, tr = threadIdx.x >> 6;
#pragma unroll
  for (int q = 0; q < 16; ++q) {
    int r = tr + q * 4;
    tl[r][tc] = f2bf(in[(size_t)(r0 + r) * C + c0 + tc]);
  }
  __syncthreads();
#pragma unroll
  for (int q = 0; q < 16; ++q) {
    int r = tr + q * 4;
    out[(size_t)(c0 + r) * R + r0 + tc] = tl[tc][r];
  }
}

// ---------------------------------------------------------------- GEMM (m97 structure)
// C(M,N) = A(M,K) @ WT(N,K)^T + bias, 128x128 tile, BK=32, 4 waves, global_load_lds
template <int OUT_F32, int BIAS_ROW>
__global__ __launch_bounds__(256) void gemm_kernel(
    const bf16* __restrict__ A, const bf16* __restrict__ WT,
    const float* __restrict__ bias, void* __restrict__ Cout,
    int M, int N, int K) {
  __shared__ bf16 ldsA[128 * 32];
  __shared__ bf16 ldsB[128 * 32];
  const int tid = threadIdx.x;
  const int lane = tid & 63;
  const int w = tid >> 6;          // wave 0..3
  const int wr = w >> 1, wc = w & 1;
  const int tileM = blockIdx.y * 128;
  const int tileN = blockIdx.x * 128;
  const int l15 = lane & 15, lg = lane >> 4;
  const int lrow = lane >> 2;          // 0..15
  const int lcol = (lane & 3) * 8;     // 0,8,16,24

  f32x4 acc[4][4] = {};

  for (int k0 = 0; k0 < K; k0 += 32) {
    async_load16(A  + (size_t)(tileM + w * 32 +      lrow) * K + k0 + lcol, &ldsA[(w * 32) * 32]);
    async_load16(A  + (size_t)(tileM + w * 32 + 16 + lrow) * K + k0 + lcol, &ldsA[(w * 32 + 16) * 32]);
    async_load16(WT + (size_t)(tileN + w * 32 +      lrow) * K + k0 + lcol, &ldsB[(w * 32) * 32]);
    async_load16(WT + (size_t)(tileN + w * 32 + 16 + lrow) * K + k0 + lcol, &ldsB[(w * 32 + 16) * 32]);
    __syncthreads();

    bf16x8 af[4], bfr[4];
#pragma unroll
    for (int i = 0; i < 4; ++i) {
      af[i]  = *(const bf16x8*)&ldsA[(wr * 64 + i * 16 + l15) * 32 + lg * 8];
      bfr[i] = *(const bf16x8*)&ldsB[(wc * 64 + i * 16 + l15) * 32 + lg * 8];
    }
#pragma unroll
    for (int i = 0; i < 4; ++i)
#pragma unroll
      for (int j = 0; j < 4; ++j)
        acc[i][j] = __builtin_amdgcn_mfma_f32_16x16x32_bf16(af[i], bfr[j], acc[i][j], 0, 0, 0);
    __syncthreads();
  }

  const int mbase = tileM + wr * 64;
  const int nbase = tileN + wc * 64;
#pragma unroll
  for (int j = 0; j < 4; ++j) {
    int col = nbase + j * 16 + l15;
    float bvc = BIAS_ROW ? 0.0f : bias[col];
#pragma unroll
    for (int i = 0; i < 4; ++i)
#pragma unroll
      for (int r = 0; r < 4; ++r) {
        int row = mbase + i * 16 + lg * 4 + r;
        float bv = BIAS_ROW ? bias[row] : bvc;
        float v = acc[i][j][r] + bv;
        if (OUT_F32) ((float*)Cout)[(size_t)row * N + col] = v;
        else         ((bf16*)Cout)[(size_t)row * N + col]  = f2bf(v);
      }
  }
}

// ---------------------------------------------------------------- combine + rope
__global__ __launch_bounds__(256) void combine_rope_kernel(
    const bf16* __restrict__ Gc, const bf16* __restrict__ Gr,
    bf16* __restrict__ out) {
  const int t = blockIdx.x * blockDim.x + threadIdx.x;   // NTOK*512 threads
  const int p = t & 511;
  const int row = t >> 9;
  const int s = row & (Ss - 1);
  // theta = 10000^(-2p)/512 ; log2(10000) = 13.287712379549449
  float theta = exp2f(-2.0f * (float)p * 13.2877123795494f) * (1.0f / 512.0f);
  float r = (float)s * theta;
  float c = cosf(r), sn = sinf(r);
  const size_t base = (size_t)row * DMODEL + 2 * p;
  const float g0 = bf2f(Gr[base]), g1 = bf2f(Gr[base + 1]);
  out[base]     = f2bf(bf2f(Gc[base])     + g0 * c - g1 * sn);
  out[base + 1] = f2bf(bf2f(Gc[base + 1]) + g1 * c + g0 * sn);
}

// ---------------------------------------------------------------- attention v2.1
// swapped-QK^T, barrier-free, LDS-free. grid (32 q-tiles of 64, 32 bh).
// Each of 4 waves owns 16 q-rows; lane (l15,lg) holds S^T col q=q0+l15.
__global__ __launch_bounds__(256) void attn_kernel(
    const bf16* __restrict__ Qn, const bf16* __restrict__ Kn,
    const bf16* __restrict__ VT, bf16* __restrict__ AO) {
  const int qt = blockIdx.x;
  const int bh = blockIdx.y;
  const int b = bh >> 4, h = bh & 15;
  const int lane = threadIdx.x & 63, w = threadIdx.x >> 6;
  const int q0 = qt * 64 + w * 16;
  const int l15 = lane & 15, lg = lane >> 4;
  const float INV_SCALE = 0.031008684f;   // 1/sqrt(16+512+512)

  // Q fragments (B-operand of swapped QK^T): Q[q=l15][d = kg*32+lg*8+e]
  const bf16* Qbase = Qn + (size_t)(b * Ss + q0 + l15) * DMODEL + h * 64;
  bf16x8 bq[2];
  bq[0] = *(const bf16x8*)&Qbase[0 * 32 + lg * 8];
  bq[1] = *(const bf16x8*)&Qbase[1 * 32 + lg * 8];

  const bf16* Kbase = Kn + (size_t)(b * Ss) * DMODEL + h * 64;
  const bf16* Vbase = VT + (size_t)(h * 64) * NTOK + b * Ss;

  float m = -3.0e38f, l = 0.0f;
  f32x4 accO[4] = {};

  for (int kv0 = 0; kv0 < Ss; kv0 += 64) {
    // ---- S^T tiles: sa[j] lane holds S[k = kv0+j*16+lg*4+r][q = q0+l15]
    f32x4 sa[4] = {};
#pragma unroll
    for (int j = 0; j < 4; ++j) {
      const bf16* kr = &Kbase[(size_t)(kv0 + j * 16 + l15) * DMODEL];
      bf16x8 ak0 = *(const bf16x8*)&kr[0 * 32 + lg * 8];
      bf16x8 ak1 = *(const bf16x8*)&kr[1 * 32 + lg * 8];
      sa[j] = __builtin_amdgcn_mfma_f32_16x16x32_bf16(ak0, bq[0], sa[j], 0, 0, 0);
      sa[j] = __builtin_amdgcn_mfma_f32_16x16x32_bf16(ak1, bq[1], sa[j], 0, 0, 0);
    }
    // ---- online softmax for q-row q0+l15 (reduce across lanes sharing l15)
    float v[4][4];
    float tmax = -3.0e38f;
#pragma unroll
    for (int j = 0; j < 4; ++j)
#pragma unroll
      for (int r = 0; r < 4; ++r) {
        v[j][r] = sa[j][r] * INV_SCALE;
        tmax = fmaxf(tmax, v[j][r]);
      }
    tmax = fmaxf(tmax, __shfl_xor(tmax, 16, 64));
    tmax = fmaxf(tmax, __shfl_xor(tmax, 32, 64));
    float mnew = fmaxf(m, tmax);
    float corr = __expf(m - mnew);           // rescale factor for q-row q0+l15
    float p[4][4];
    float ts = 0.0f;
#pragma unroll
    for (int j = 0; j < 4; ++j)
#pragma unroll
      for (int r = 0; r < 4; ++r) {
        p[j][r] = __expf(v[j][r] - mnew);
        ts += p[j][r];
      }
    ts += __shfl_xor(ts, 16, 64);
    ts += __shfl_xor(ts, 32, 64);
    m = mnew;
    l = l * corr + ts;
    // accO rows are q = q0+lg*4+r -> fetch THAT row's corr (state is uniform
    // across the 4 lanes sharing l15, so lane lg*4+r holds row lg*4+r's corr)
    float corr_r[4];
#pragma unroll
    for (int r = 0; r < 4; ++r) corr_r[r] = __shfl(corr, lg * 4 + r, 64);
#pragma unroll
    for (int dj = 0; dj < 4; ++dj)
#pragma unroll
      for (int r = 0; r < 4; ++r) accO[dj][r] *= corr_r[r];

    // ---- pack P to bf16 pairs: W[j][hh] = (p[j][2hh], p[j][2hh+1])
    unsigned int W[4][2];
#pragma unroll
    for (int j = 0; j < 4; ++j) {
      W[j][0] = packbf(p[j][0], p[j][1]);
      W[j][1] = packbf(p[j][2], p[j][3]);
    }
    // ---- redistribute to PV A-frag layout: A[q=l15][k=kp*32+lg*8+e]
    const int src_a = l15 + 32 * (lg & 1);
    unsigned int Sa[4][2], Sb[4][2];
#pragma unroll
    for (int j = 0; j < 4; ++j)
#pragma unroll
      for (int hh = 0; hh < 2; ++hh) {
        Sa[j][hh] = __shfl(W[j][hh], src_a, 64);
        Sb[j][hh] = __shfl(W[j][hh], src_a + 16, 64);
      }
    const bool hi = ((lg >> 1) & 1) != 0;
    // ---- O += P V  (B-frag: V^T[d=dj*16+l15][k])
#pragma unroll
    for (int kp = 0; kp < 2; ++kp) {
      union { bf16x8 v8; unsigned int u[4]; } pa;
      const int j0 = kp * 2;
      pa.u[0] = hi ? Sa[j0 + 1][0] : Sa[j0][0];
      pa.u[1] = hi ? Sa[j0 + 1][1] : Sa[j0][1];
      pa.u[2] = hi ? Sb[j0 + 1][0] : Sb[j0][0];
      pa.u[3] = hi ? Sb[j0 + 1][1] : Sb[j0][1];
#pragma unroll
      for (int dj = 0; dj < 4; ++dj) {
        bf16x8 bv = *(const bf16x8*)&Vbase[(size_t)(dj * 16 + l15) * NTOK + kv0 + kp * 32 + lg * 8];
        accO[dj] = __builtin_amdgcn_mfma_f32_16x16x32_bf16(pa.v8, bv, accO[dj], 0, 0, 0);
      }
    }
  }

  // ---- epilogue: O[q=q0+lg*4+r][d=dj*16+l15]; l for row lg*4+r lives at lane lg*4+r
  float linv[4];
#pragma unroll
  for (int r = 0; r < 4; ++r) linv[r] = 1.0f / __shfl(l, lg * 4 + r, 64);
#pragma unroll
  for (int dj = 0; dj < 4; ++dj)
#pragma unroll
    for (int r = 0; r < 4; ++r)
      AO[(size_t)(b * Ss + q0 + lg * 4 + r) * DMODEL + h * 64 + dj * 16 + l15] =
          f2bf(accO[dj][r] * linv[r]);
}

// ---------------------------------------------------------------- launch
extern "C" void kernel_launch(void* const* d_in, const int* in_sizes, int n_in,
                              void* d_out, int out_size, void* d_ws, size_t ws_size,
                              hipStream_t stream) {
  const float* x      = (const float*)d_in[0];
  const float* Wdq    = (const float*)d_in[1];  const float* Wdq_b  = (const float*)d_in[2];
  const float* Wuq    = (const float*)d_in[3];  const float* Wuq_b  = (const float*)d_in[4];
  const float* Wqr    = (const float*)d_in[5];  const float* Wqr_b  = (const float*)d_in[6];
  const float* Wkr    = (const float*)d_in[7];  const float* Wkr_b  = (const float*)d_in[8];
  const float* Wdkv   = (const float*)d_in[9];  const float* Wdkv_b = (const float*)d_in[10];
  const float* Wuk    = (const float*)d_in[11]; const float* Wuk_b  = (const float*)d_in[12];
  const float* Wuv    = (const float*)d_in[13]; const float* Wuv_b  = (const float*)d_in[14];
  const float* Wo     = (const float*)d_in[15]; const float* Wo_b   = (const float*)d_in[16];

  // ---- workspace slots ----
  char* ws = (char*)d_ws;
  size_t off = 0;
  bf16* WdqT   = (bf16*)(ws + off); off += (size_t)512  * 1024 * 2;
  bf16* WuqT   = (bf16*)(ws + off); off += (size_t)1024 * 512  * 2;
  bf16* WqrT   = (bf16*)(ws + off); off += (size_t)1024 * 512  * 2;
  bf16* WkrT   = (bf16*)(ws + off); off += (size_t)1024 * 1024 * 2;
  bf16* WdkvT  = (bf16*)(ws + off); off += (size_t)512  * 1024 * 2;
  bf16* WukT   = (bf16*)(ws + off); off += (size_t)1024 * 512  * 2;
  bf16* WuvT   = (bf16*)(ws + off); off += (size_t)1024 * 512  * 2;
  bf16* WoT    = (bf16*)(ws + off); off += (size_t)1024 * 1024 * 2;
  bf16* x_bf   = (bf16*)(ws + off); off += (size_t)NTOK * 1024 * 2;
  bf16* ct_q   = (bf16*)(ws + off); off += (size_t)NTOK * 512 * 2;
  bf16* ct_kv  = (bf16*)(ws + off); off += (size_t)NTOK * 512 * 2;
  bf16* Ga     = (bf16*)(ws + off); off += (size_t)NTOK * 1024 * 2;
  bf16* Gb     = (bf16*)(ws + off); off += (size_t)NTOK * 1024 * 2;
  bf16* VTr    = (bf16*)(ws + off); off += (size_t)NTOK * 1024 * 2;
  bf16* Qn     = (bf16*)d_out;                       // dead before final GEMM
  bf16* Kn     = (bf16*)d_out + (size_t)NTOK * DMODEL;
  bf16* AO     = Ga;
  (void)ws_size; (void)in_sizes; (void)n_in; (void)out_size;

  // fused weight transpose+convert (tile starts: 128 tiles per 512x1024, 256 per 1024x1024)
  TransPack tp = {{
    { Wdq,  WdqT,  1024, 512,  0    },
    { Wuq,  WuqT,  512,  1024, 128  },
    { Wqr,  WqrT,  512,  1024, 256  },
    { Wkr,  WkrT,  1024, 1024, 384  },
    { Wdkv, WdkvT, 1024, 512,  640  },
    { Wuk,  WukT,  512,  1024, 768  },
    { Wuv,  WuvT,  512,  1024, 896  },
    { Wo,   WoT,   1024, 1024, 1024 },
  }};
  transpose8_kernel<<<1280, 256, 0, stream>>>(tp);
  convert_kernel<<<(NTOK * DMODEL / 4 + 255) / 256, 256, 0, stream>>>(x, x_bf, NTOK * DMODEL / 4);

  // down-projections
  gemm_kernel<0, 0><<<dim3(4, 32), 256, 0, stream>>>(x_bf, WdqT,  Wdq_b,  ct_q,  NTOK, 512, 1024);
  gemm_kernel<0, 0><<<dim3(4, 32), 256, 0, stream>>>(x_bf, WdkvT, Wdkv_b, ct_kv, NTOK, 512, 1024);

  // query = up(ct_q) + rope(qr(ct_q)) -> Qn
  gemm_kernel<0, 0><<<dim3(8, 32), 256, 0, stream>>>(ct_q, WuqT, Wuq_b, Ga, NTOK, 1024, 512);
  gemm_kernel<0, 0><<<dim3(8, 32), 256, 0, stream>>>(ct_q, WqrT, Wqr_b, Gb, NTOK, 1024, 512);
  combine_rope_kernel<<<(NTOK * 512) / 256, 256, 0, stream>>>(Ga, Gb, Qn);

  // V^T directly: VT[d][token] = Wuv^T @ ct_kv^T  (M=1024 d, N=4096 tokens, K=512)
  gemm_kernel<0, 1><<<dim3(32, 8), 256, 0, stream>>>(WuvT, ct_kv, Wuv_b, VTr, 1024, NTOK, 512);

  // key = up(ct_kv) + rope(kr(x)) -> Kn
  gemm_kernel<0, 0><<<dim3(8, 32), 256, 0, stream>>>(ct_kv, WukT, Wuk_b, Ga, NTOK, 1024, 512);
  gemm_kernel<0, 0><<<dim3(8, 32), 256, 0, stream>>>(x_bf,  WkrT, Wkr_b, Gb, NTOK, 1024, 1024);
  combine_rope_kernel<<<(NTOK * 512) / 256, 256, 0, stream>>>(Ga, Gb, Kn);

  // attention: Qn, Kn, VTr -> AO (aliases Ga)
  attn_kernel<<<dim3(32, 32), 256, 0, stream>>>(Qn, Kn, VTr, AO);

  // output projection (reads AO, writes fp32 d_out)
  gemm_kernel<1, 0><<<dim3(8, 32), 256, 0, stream>>>(AO, WoT, Wo_b, (float*)d_out, NTOK, 1024, 1024);
}

// Round 6
// 240.972 us; speedup vs baseline: 1.9822x; 1.9822x over previous
//
#include <hip/hip_runtime.h>
#include <hip/hip_bf16.h>
#include <math.h>

typedef __hip_bfloat16 bf16;
typedef __bf16 bf16x8 __attribute__((ext_vector_type(8)));
typedef float  f32x4  __attribute__((ext_vector_type(4)));

#define DEVI __device__ __forceinline__

static constexpr int Bb     = 2;
static constexpr int Ss     = 2048;
static constexpr int DMODEL = 1024;
static constexpr int NTOK   = Bb * Ss;   // 4096

DEVI float bf2f(bf16 v) { return __bfloat162float(v); }
DEVI bf16  f2bf(float v) { return __float2bfloat16(v); }

DEVI unsigned int packbf(float lo, float hi) {
  union { bf16 b; unsigned short u; } a, c;
  a.b = f2bf(lo); c.b = f2bf(hi);
  return ((unsigned int)c.u << 16) | a.u;
}
DEVI float bfu2f(unsigned short u) {
  unsigned int x = (unsigned int)u << 16;
  float f; __builtin_memcpy(&f, &x, 4); return f;
}

DEVI void async_load16(const bf16* g, bf16* l) {
  __builtin_amdgcn_global_load_lds((const __attribute__((address_space(1))) void*)g,
                                   (__attribute__((address_space(3))) void*)l, 16, 0, 0);
}

// ---------------------------------------------------------------- fp32 -> bf16 convert
__global__ __launch_bounds__(256) void convert_kernel(
    const float* __restrict__ in, bf16* __restrict__ out, int n4) {
  const int t = blockIdx.x * blockDim.x + threadIdx.x;
  if (t >= n4) return;
  const float4 v = ((const float4*)in)[t];
  uint2 o; o.x = packbf(v.x, v.y); o.y = packbf(v.z, v.w);
  *(uint2*)&out[(size_t)t * 4] = o;
}

// ---------------------------------------------------------------- fused weight transpose
struct TransDesc { const float* src; bf16* dst; int R; int C; int tstart; };
struct TransPack { TransDesc d[8]; };

__global__ __launch_bounds__(256) void transpose8_kernel(TransPack p) {
  const int t = blockIdx.x;
  int i = 0;
#pragma unroll
  for (int j = 1; j < 8; ++j) if (t >= p.d[j].tstart) i = j;
  const float* __restrict__ in = p.d[i].src;
  bf16* __restrict__ out = p.d[i].dst;
  const int R = p.d[i].R, C = p.d[i].C;
  const int rel = t - p.d[i].tstart;
  const int tilesC = C >> 6;
  const int r0 = (rel / tilesC) * 64, c0 = (rel % tilesC) * 64;

  __shared__ bf16 tl[64][65];
  const int tc = threadIdx.x & 63, tr = threadIdx.x >> 6;
#pragma unroll
  for (int q = 0; q < 16; ++q) {
    int r = tr + q * 4;
    tl[r][tc] = f2bf(in[(size_t)(r0 + r) * C + c0 + tc]);
  }
  __syncthreads();
#pragma unroll
  for (int q = 0; q < 16; ++q) {
    int r = tr + q * 4;
    out[(size_t)(c0 + r) * R + r0 + tc] = tl[tc][r];
  }
}

// ---------------------------------------------------------------- GEMM (m97 structure)
// C(M,N) = A(M,K;lda) @ WT(N,K;ldb)^T + bias, 128x128 tile, BK=32, global_load_lds
template <int OUT_F32, int BIAS_ROW>
__global__ __launch_bounds__(256) void gemm_kernel(
    const bf16* __restrict__ A, int lda,
    const bf16* __restrict__ WT, int ldb,
    const float* __restrict__ b1, const float* __restrict__ b2, int bsplit,
    void* __restrict__ Cout, int ldc, int K) {
  __shared__ bf16 ldsA[128 * 32];
  __shared__ bf16 ldsB[128 * 32];
  const int tid = threadIdx.x;
  const int lane = tid & 63;
  const int w = tid >> 6;
  const int wr = w >> 1, wc = w & 1;
  const int tileM = blockIdx.y * 128;
  const int tileN = blockIdx.x * 128;
  const int l15 = lane & 15, lg = lane >> 4;
  const int lrow = lane >> 2;
  const int lcol = (lane & 3) * 8;

  f32x4 acc[4][4] = {};

  for (int k0 = 0; k0 < K; k0 += 32) {
    async_load16(A  + (size_t)(tileM + w * 32 +      lrow) * lda + k0 + lcol, &ldsA[(w * 32) * 32]);
    async_load16(A  + (size_t)(tileM + w * 32 + 16 + lrow) * lda + k0 + lcol, &ldsA[(w * 32 + 16) * 32]);
    async_load16(WT + (size_t)(tileN + w * 32 +      lrow) * ldb + k0 + lcol, &ldsB[(w * 32) * 32]);
    async_load16(WT + (size_t)(tileN + w * 32 + 16 + lrow) * ldb + k0 + lcol, &ldsB[(w * 32 + 16) * 32]);
    __syncthreads();

    bf16x8 af[4], bfr[4];
#pragma unroll
    for (int i = 0; i < 4; ++i) {
      af[i]  = *(const bf16x8*)&ldsA[(wr * 64 + i * 16 + l15) * 32 + lg * 8];
      bfr[i] = *(const bf16x8*)&ldsB[(wc * 64 + i * 16 + l15) * 32 + lg * 8];
    }
#pragma unroll
    for (int i = 0; i < 4; ++i)
#pragma unroll
      for (int j = 0; j < 4; ++j)
        acc[i][j] = __builtin_amdgcn_mfma_f32_16x16x32_bf16(af[i], bfr[j], acc[i][j], 0, 0, 0);
    __syncthreads();
  }

  const int mbase = tileM + wr * 64;
  const int nbase = tileN + wc * 64;
#pragma unroll
  for (int j = 0; j < 4; ++j) {
    int col = nbase + j * 16 + l15;
    float bvc = BIAS_ROW ? 0.0f : (col < bsplit ? b1[col] : b2[col - bsplit]);
#pragma unroll
    for (int i = 0; i < 4; ++i)
#pragma unroll
      for (int r = 0; r < 4; ++r) {
        int row = mbase + i * 16 + lg * 4 + r;
        float bv = BIAS_ROW ? b1[row] : bvc;
        float v = acc[i][j][r] + bv;
        if (OUT_F32) ((float*)Cout)[(size_t)row * ldc + col] = v;
        else         ((bf16*)Cout)[(size_t)row * ldc + col]  = f2bf(v);
      }
  }
}

// ---------------------------------------------------------------- combine + rope (vectorized)
// out[row][:] = Gc[row][:] + rope(Gr[row][:]); 8 elems (4 pairs) per thread
__global__ __launch_bounds__(256) void combine_rope_kernel(
    const bf16* __restrict__ Gc, int ldc_,
    const bf16* __restrict__ Gr, int ldr_,
    bf16* __restrict__ out) {
  const int t = blockIdx.x * blockDim.x + threadIdx.x;   // NTOK*128
  const int g = t & 127, row = t >> 7;
  const int s = row & (Ss - 1);
  union { bf16x8 v; unsigned short u[8]; } vc, vr;
  vc.v = *(const bf16x8*)&Gc[(size_t)row * ldc_ + (size_t)g * 8];
  vr.v = *(const bf16x8*)&Gr[(size_t)row * ldr_ + (size_t)g * 8];
  uint4 o;
  unsigned int* op = &o.x;
#pragma unroll
  for (int qq = 0; qq < 4; ++qq) {
    const int p = g * 4 + qq;
    float c, sn;
    if (p == 0) {
      float rr = (float)s * (1.0f / 512.0f);
      c = cosf(rr); sn = sinf(rr);
    } else {
      // theta = 10000^(-2p)/512; for p>=1, r <= 4e-8 -> cosf(r)==1.0f, sinf(r)==r (fp32-exact)
      float theta = exp2f(-26.5754247590989f * (float)p) * (1.0f / 512.0f);
      sn = (float)s * theta; c = 1.0f;
    }
    float g0 = bfu2f(vr.u[2 * qq]), g1 = bfu2f(vr.u[2 * qq + 1]);
    float c0 = bfu2f(vc.u[2 * qq]), c1 = bfu2f(vc.u[2 * qq + 1]);
    op[qq] = packbf(c0 + g0 * c - g1 * sn, c1 + g1 * c + g0 * sn);
  }
  *(uint4*)&out[(size_t)row * DMODEL + (size_t)g * 8] = o;
}

// ---------------------------------------------------------------- attention v3
// grid (16 qt, 32 bh), 4 waves x 32 q-rows. K/V staged in LDS (dbuf, XOR-swizzled,
// pre-swizzled global source). Swapped QK^T; register softmax; wave-private P LDS.
__global__ __launch_bounds__(256) void attn_kernel(
    const bf16* __restrict__ Qn, const bf16* __restrict__ Kn,
    const bf16* __restrict__ VT, bf16* __restrict__ AO) {
  const int qt = blockIdx.x, bh = blockIdx.y;
  const int b = bh >> 4, h = bh & 15;
  const int tid = threadIdx.x, lane = tid & 63, w = tid >> 6;
  const int q0 = qt * 128 + w * 32;
  const int l15 = lane & 15, lg = lane >> 4;
  const float INV_SCALE = 0.031008684f;   // 1/sqrt(16+512+512)

  __shared__ bf16 ldsK[2][64 * 64];   // [kv-row][d], rows 128B, XOR-swizzled
  __shared__ bf16 ldsV[2][64 * 64];   // [d-row][token], XOR-swizzled
  __shared__ bf16 ldsP[4][32 * 64];   // per-wave [q][k], XOR-swizzled

  const bf16* Kg = Kn + (size_t)(b * Ss) * DMODEL + h * 64;
  const bf16* Vg = VT + (size_t)(h * 64) * NTOK + b * Ss;

  // stage helper: linear LDS dest + inverse-swizzled global source (rule #21)
  auto stage = [&](int bs, int kv0) {
#pragma unroll
    for (int half = 0; half < 2; ++half) {
      const int c = half * 256 + tid;              // chunk 0..511 (16B each)
      const int r = c >> 3;
      const int srcb = ((c & 7) * 16) ^ ((r & 7) << 4);
      async_load16((const bf16*)((const char*)(Kg + (size_t)(kv0 + r) * DMODEL) + srcb),
                   &ldsK[bs][(half * 256 + w * 64) * 8]);
      async_load16((const bf16*)((const char*)(Vg + (size_t)r * NTOK + kv0) + srcb),
                   &ldsV[bs][(half * 256 + w * 64) * 8]);
    }
  };

  // Q B-frags: Q[q0 + i*16 + l15][d = kg*32 + lg*8 + e]
  const bf16* Qbase = Qn + (size_t)(b * Ss + q0 + l15) * DMODEL + h * 64;
  bf16x8 bq[2][2];
#pragma unroll
  for (int i = 0; i < 2; ++i)
#pragma unroll
    for (int kg = 0; kg < 2; ++kg)
      bq[i][kg] = *(const bf16x8*)&Qbase[(size_t)(i * 16) * DMODEL + kg * 32 + lg * 8];

  float m[2] = { -3.0e38f, -3.0e38f }, l[2] = { 0.f, 0.f };
  f32x4 accO[2][4] = {};

  const int kswz = (l15 & 7) << 4;          // byte XOR for K/V/P reads (row&7 == l15&7)
  char* Pw = (char*)&ldsP[w][0];

  stage(0, 0);
  for (int t = 0; t < 32; ++t) {
    const int cur = t & 1;
    __syncthreads();                         // all waves done reading buf[cur^1]
    if (t < 31) stage(cur ^ 1, (t + 1) * 64);
    __syncthreads();                         // stage(t) drained (vmcnt0 at barrier)

    const char* Kl = (const char*)&ldsK[cur][0];
    const char* Vl = (const char*)&ldsV[cur][0];

    // ---- S^T: sa[j][i] holds S[k = t*64 + j*16 + lg*4 + r][q = q0 + i*16 + l15]
    f32x4 sa[4][2] = {};
#pragma unroll
    for (int j = 0; j < 4; ++j) {
      const int row = j * 16 + l15;
      bf16x8 ak0 = *(const bf16x8*)(Kl + row * 128 + ((lg * 16) ^ kswz));
      bf16x8 ak1 = *(const bf16x8*)(Kl + row * 128 + ((64 + lg * 16) ^ kswz));
#pragma unroll
      for (int i = 0; i < 2; ++i) {
        sa[j][i] = __builtin_amdgcn_mfma_f32_16x16x32_bf16(ak0, bq[i][0], sa[j][i], 0, 0, 0);
        sa[j][i] = __builtin_amdgcn_mfma_f32_16x16x32_bf16(ak1, bq[i][1], sa[j][i], 0, 0, 0);
      }
    }

    // ---- online softmax per q-subtile; write P (wave-private, swizzled)
    float corr[2];
#pragma unroll
    for (int i = 0; i < 2; ++i) {
      float p[4][4];
      float tmax = -3.0e38f;
#pragma unroll
      for (int j = 0; j < 4; ++j)
#pragma unroll
        for (int r = 0; r < 4; ++r) {
          p[j][r] = sa[j][i][r] * INV_SCALE;
          tmax = fmaxf(tmax, p[j][r]);
        }
      tmax = fmaxf(tmax, __shfl_xor(tmax, 16, 64));
      tmax = fmaxf(tmax, __shfl_xor(tmax, 32, 64));
      float mnew = fmaxf(m[i], tmax);
      corr[i] = __expf(m[i] - mnew);
      float ts = 0.f;
#pragma unroll
      for (int j = 0; j < 4; ++j)
#pragma unroll
        for (int r = 0; r < 4; ++r) {
          p[j][r] = __expf(p[j][r] - mnew);
          ts += p[j][r];
        }
      ts += __shfl_xor(ts, 16, 64);
      ts += __shfl_xor(ts, 32, 64);
      m[i] = mnew;
      l[i] = l[i] * corr[i] + ts;
      const int q = i * 16 + l15;
#pragma unroll
      for (int j = 0; j < 4; ++j) {
        uint2 pw;
        pw.x = packbf(p[j][0], p[j][1]);
        pw.y = packbf(p[j][2], p[j][3]);
        const int chunk = (j * 2 + (lg >> 1)) ^ (q & 7);
        *(uint2*)(Pw + q * 128 + chunk * 16 + (lg & 1) * 8) = pw;
      }
    }

    // ---- rescale accO (rows q = q0 + i*16 + lg*4 + r; corr lives at lane l15 = row)
#pragma unroll
    for (int i = 0; i < 2; ++i) {
      float cr[4];
#pragma unroll
      for (int r = 0; r < 4; ++r) cr[r] = __shfl(corr[i], lg * 4 + r, 64);
#pragma unroll
      for (int dj = 0; dj < 4; ++dj)
#pragma unroll
        for (int r = 0; r < 4; ++r) accO[i][dj][r] *= cr[r];
    }

    // ---- O += P V
    bf16x8 bv[4][2];
#pragma unroll
    for (int dj = 0; dj < 4; ++dj) {
      const int vrow = dj * 16 + l15;
      bv[dj][0] = *(const bf16x8*)(Vl + vrow * 128 + ((lg * 16) ^ kswz));
      bv[dj][1] = *(const bf16x8*)(Vl + vrow * 128 + ((64 + lg * 16) ^ kswz));
    }
#pragma unroll
    for (int i = 0; i < 2; ++i) {
      const int q = i * 16 + l15;
      bf16x8 pa0 = *(const bf16x8*)(Pw + q * 128 + ((lg * 16) ^ kswz));
      bf16x8 pa1 = *(const bf16x8*)(Pw + q * 128 + ((64 + lg * 16) ^ kswz));
#pragma unroll
      for (int dj = 0; dj < 4; ++dj) {
        accO[i][dj] = __builtin_amdgcn_mfma_f32_16x16x32_bf16(pa0, bv[dj][0], accO[i][dj], 0, 0, 0);
        accO[i][dj] = __builtin_amdgcn_mfma_f32_16x16x32_bf16(pa1, bv[dj][1], accO[i][dj], 0, 0, 0);
      }
    }
  }

  // ---- epilogue
#pragma unroll
  for (int i = 0; i < 2; ++i) {
    float linv[4];
#pragma unroll
    for (int r = 0; r < 4; ++r) linv[r] = 1.0f / __shfl(l[i], lg * 4 + r, 64);
#pragma unroll
    for (int dj = 0; dj < 4; ++dj)
#pragma unroll
      for (int r = 0; r < 4; ++r)
        AO[(size_t)(b * Ss + q0 + i * 16 + lg * 4 + r) * DMODEL + h * 64 + dj * 16 + l15] =
            f2bf(accO[i][dj][r] * linv[r]);
  }
}

// ---------------------------------------------------------------- launch
extern "C" void kernel_launch(void* const* d_in, const int* in_sizes, int n_in,
                              void* d_out, int out_size, void* d_ws, size_t ws_size,
                              hipStream_t stream) {
  const float* x      = (const float*)d_in[0];
  const float* Wdq    = (const float*)d_in[1];  const float* Wdq_b  = (const float*)d_in[2];
  const float* Wuq    = (const float*)d_in[3];  const float* Wuq_b  = (const float*)d_in[4];
  const float* Wqr    = (const float*)d_in[5];  const float* Wqr_b  = (const float*)d_in[6];
  const float* Wkr    = (const float*)d_in[7];  const float* Wkr_b  = (const float*)d_in[8];
  const float* Wdkv   = (const float*)d_in[9];  const float* Wdkv_b = (const float*)d_in[10];
  const float* Wuk    = (const float*)d_in[11]; const float* Wuk_b  = (const float*)d_in[12];
  const float* Wuv    = (const float*)d_in[13]; const float* Wuv_b  = (const float*)d_in[14];
  const float* Wo     = (const float*)d_in[15]; const float* Wo_b   = (const float*)d_in[16];

  // ---- workspace (~50 MB): weights ordered for GEMM fusion adjacency ----
  char* ws = (char*)d_ws;
  size_t off = 0;
  bf16* WdqT   = (bf16*)(ws + off); off += (size_t)512  * 1024 * 2;   // down pair
  bf16* WdkvT  = (bf16*)(ws + off); off += (size_t)512  * 1024 * 2;
  bf16* WuqT   = (bf16*)(ws + off); off += (size_t)1024 * 512  * 2;   // upQ pair
  bf16* WqrT   = (bf16*)(ws + off); off += (size_t)1024 * 512  * 2;
  bf16* WukT   = (bf16*)(ws + off); off += (size_t)1024 * 512  * 2;
  bf16* WuvT   = (bf16*)(ws + off); off += (size_t)1024 * 512  * 2;
  bf16* WkrT   = (bf16*)(ws + off); off += (size_t)1024 * 1024 * 2;
  bf16* WoT    = (bf16*)(ws + off); off += (size_t)1024 * 1024 * 2;
  bf16* x_bf   = (bf16*)(ws + off); off += (size_t)NTOK * 1024 * 2;
  bf16* ct     = (bf16*)(ws + off); off += (size_t)NTOK * 1024 * 2;   // [ct_q | ct_kv]
  bf16* Ga     = (bf16*)(ws + off); off += (size_t)NTOK * 1024 * 2;
  bf16* Gb     = (bf16*)(ws + off); off += (size_t)NTOK * 1024 * 2;
  bf16* VTr    = (bf16*)(ws + off); off += (size_t)NTOK * 1024 * 2;
  bf16* Gq     = Ga;                                  // fused upQ output spans Ga+Gb
  bf16* Qn     = (bf16*)d_out;                        // dead before final GEMM
  bf16* Kn     = (bf16*)d_out + (size_t)NTOK * DMODEL;
  bf16* AO     = Ga;
  (void)ws_size; (void)in_sizes; (void)n_in; (void)out_size;

  TransPack tp = {{
    { Wdq,  WdqT,  1024, 512,  0    },
    { Wdkv, WdkvT, 1024, 512,  128  },
    { Wuq,  WuqT,  512,  1024, 256  },
    { Wqr,  WqrT,  512,  1024, 384  },
    { Wuk,  WukT,  512,  1024, 512  },
    { Wuv,  WuvT,  512,  1024, 640  },
    { Wkr,  WkrT,  1024, 1024, 768  },
    { Wo,   WoT,   1024, 1024, 1024 },
  }};
  transpose8_kernel<<<1280, 256, 0, stream>>>(tp);
  convert_kernel<<<(NTOK * DMODEL / 4 + 255) / 256, 256, 0, stream>>>(x, x_bf, NTOK * DMODEL / 4);

  // fused down-projection: ct = x @ [Wdq|Wdkv]  (N=1024, K=1024)
  gemm_kernel<0, 0><<<dim3(8, 32), 256, 0, stream>>>(
      x_bf, 1024, WdqT, 1024, Wdq_b, Wdkv_b, 512, ct, 1024, 1024);

  // fused up-Q: Gq = ct_q @ [Wuq|Wqr]  (N=2048, K=512)
  gemm_kernel<0, 0><<<dim3(16, 32), 256, 0, stream>>>(
      ct, 1024, WuqT, 512, Wuq_b, Wqr_b, 1024, Gq, 2048, 512);
  combine_rope_kernel<<<NTOK * 128 / 256, 256, 0, stream>>>(Gq, 2048, Gq + 1024, 2048, Qn);

  // V^T directly: VT[d][tok] = Wuv^T @ ct_kv^T  (M=1024, N=4096, K=512)
  gemm_kernel<0, 1><<<dim3(32, 8), 256, 0, stream>>>(
      WuvT, 512, ct + 512, 1024, Wuv_b, Wuv_b, NTOK, VTr, NTOK, 512);

  // key = up(ct_kv) + rope(kr(x))
  gemm_kernel<0, 0><<<dim3(8, 32), 256, 0, stream>>>(
      ct + 512, 1024, WukT, 512, Wuk_b, Wuk_b, 1024, Ga, 1024, 512);
  gemm_kernel<0, 0><<<dim3(8, 32), 256, 0, stream>>>(
      x_bf, 1024, WkrT, 1024, Wkr_b, Wkr_b, 1024, Gb, 1024, 1024);
  combine_rope_kernel<<<NTOK * 128 / 256, 256, 0, stream>>>(Ga, 1024, Gb, 1024, Kn);

  // attention
  attn_kernel<<<dim3(16, 32), 256, 0, stream>>>(Qn, Kn, VTr, AO);

  // output projection (fp32 out)
  gemm_kernel<1, 0><<<dim3(8, 32), 256, 0, stream>>>(
      AO, 1024, WoT, 1024, Wo_b, Wo_b, 1024, (float*)d_out, 1024, 1024);
}

// Round 7
// 238.802 us; speedup vs baseline: 2.0002x; 1.0091x over previous
//
#include <hip/hip_runtime.h>
#include <hip/hip_bf16.h>
#include <math.h>

typedef __hip_bfloat16 bf16;
typedef __bf16 bf16x8 __attribute__((ext_vector_type(8)));
typedef float  f32x4  __attribute__((ext_vector_type(4)));

#define DEVI __device__ __forceinline__

static constexpr int Bb     = 2;
static constexpr int Ss     = 2048;
static constexpr int DMODEL = 1024;
static constexpr int NTOK   = Bb * Ss;   // 4096

DEVI float bf2f(bf16 v) { return __bfloat162float(v); }
DEVI bf16  f2bf(float v) { return __float2bfloat16(v); }

DEVI unsigned int packbf(float lo, float hi) {
  union { bf16 b; unsigned short u; } a, c;
  a.b = f2bf(lo); c.b = f2bf(hi);
  return ((unsigned int)c.u << 16) | a.u;
}
DEVI float bfu2f(unsigned short u) {
  unsigned int x = (unsigned int)u << 16;
  float f; __builtin_memcpy(&f, &x, 4); return f;
}

DEVI void async_load16(const bf16* g, bf16* l) {
  __builtin_amdgcn_global_load_lds((const __attribute__((address_space(1))) void*)g,
                                   (__attribute__((address_space(3))) void*)l, 16, 0, 0);
}

// ---------------------------------------------------------------- fp32 -> bf16 convert
__global__ __launch_bounds__(256) void convert_kernel(
    const float* __restrict__ in, bf16* __restrict__ out, int n4) {
  const int t = blockIdx.x * blockDim.x + threadIdx.x;
  if (t >= n4) return;
  const float4 v = ((const float4*)in)[t];
  uint2 o; o.x = packbf(v.x, v.y); o.y = packbf(v.z, v.w);
  *(uint2*)&out[(size_t)t * 4] = o;
}

// ---------------------------------------------------------------- fused weight transpose
struct TransDesc { const float* src; bf16* dst; int R; int C; int tstart; };
struct TransPack { TransDesc d[8]; };

__global__ __launch_bounds__(256) void transpose8_kernel(TransPack p) {
  const int t = blockIdx.x;
  int i = 0;
#pragma unroll
  for (int j = 1; j < 8; ++j) if (t >= p.d[j].tstart) i = j;
  const float* __restrict__ in = p.d[i].src;
  bf16* __restrict__ out = p.d[i].dst;
  const int R = p.d[i].R, C = p.d[i].C;
  const int rel = t - p.d[i].tstart;
  const int tilesC = C >> 6;
  const int r0 = (rel / tilesC) * 64, c0 = (rel % tilesC) * 64;

  __shared__ bf16 tl[64][65];
  const int tc = threadIdx.x & 63, tr = threadIdx.x >> 6;
#pragma unroll
  for (int q = 0; q < 16; ++q) {
    int r = tr + q * 4;
    tl[r][tc] = f2bf(in[(size_t)(r0 + r) * C + c0 + tc]);
  }
  __syncthreads();
#pragma unroll
  for (int q = 0; q < 16; ++q) {
    int r = tr + q * 4;
    out[(size_t)(c0 + r) * R + r0 + tc] = tl[tc][r];
  }
}

// ---------------------------------------------------------------- GEMM (m97 structure)
// C(M,N) = A(M,K;lda) @ WT(N,K;ldb)^T + bias, 128x128 tile, BK=32, global_load_lds
template <int OUT_F32, int BIAS_ROW>
__global__ __launch_bounds__(256) void gemm_kernel(
    const bf16* __restrict__ A, int lda,
    const bf16* __restrict__ WT, int ldb,
    const float* __restrict__ b1, const float* __restrict__ b2, int bsplit,
    void* __restrict__ Cout, int ldc, int K) {
  __shared__ bf16 ldsA[128 * 32];
  __shared__ bf16 ldsB[128 * 32];
  const int tid = threadIdx.x;
  const int lane = tid & 63;
  const int w = tid >> 6;
  const int wr = w >> 1, wc = w & 1;
  const int tileM = blockIdx.y * 128;
  const int tileN = blockIdx.x * 128;
  const int l15 = lane & 15, lg = lane >> 4;
  const int lrow = lane >> 2;
  const int lcol = (lane & 3) * 8;

  f32x4 acc[4][4] = {};

  for (int k0 = 0; k0 < K; k0 += 32) {
    async_load16(A  + (size_t)(tileM + w * 32 +      lrow) * lda + k0 + lcol, &ldsA[(w * 32) * 32]);
    async_load16(A  + (size_t)(tileM + w * 32 + 16 + lrow) * lda + k0 + lcol, &ldsA[(w * 32 + 16) * 32]);
    async_load16(WT + (size_t)(tileN + w * 32 +      lrow) * ldb + k0 + lcol, &ldsB[(w * 32) * 32]);
    async_load16(WT + (size_t)(tileN + w * 32 + 16 + lrow) * ldb + k0 + lcol, &ldsB[(w * 32 + 16) * 32]);
    __syncthreads();

    bf16x8 af[4], bfr[4];
#pragma unroll
    for (int i = 0; i < 4; ++i) {
      af[i]  = *(const bf16x8*)&ldsA[(wr * 64 + i * 16 + l15) * 32 + lg * 8];
      bfr[i] = *(const bf16x8*)&ldsB[(wc * 64 + i * 16 + l15) * 32 + lg * 8];
    }
#pragma unroll
    for (int i = 0; i < 4; ++i)
#pragma unroll
      for (int j = 0; j < 4; ++j)
        acc[i][j] = __builtin_amdgcn_mfma_f32_16x16x32_bf16(af[i], bfr[j], acc[i][j], 0, 0, 0);
    __syncthreads();
  }

  const int mbase = tileM + wr * 64;
  const int nbase = tileN + wc * 64;
#pragma unroll
  for (int j = 0; j < 4; ++j) {
    int col = nbase + j * 16 + l15;
    float bvc = BIAS_ROW ? 0.0f : (col < bsplit ? b1[col] : b2[col - bsplit]);
#pragma unroll
    for (int i = 0; i < 4; ++i)
#pragma unroll
      for (int r = 0; r < 4; ++r) {
        int row = mbase + i * 16 + lg * 4 + r;
        float bv = BIAS_ROW ? b1[row] : bvc;
        float v = acc[i][j][r] + bv;
        if (OUT_F32) ((float*)Cout)[(size_t)row * ldc + col] = v;
        else         ((bf16*)Cout)[(size_t)row * ldc + col]  = f2bf(v);
      }
  }
}

// ---------------------------------------------------------------- combine + rope (vectorized)
__global__ __launch_bounds__(256) void combine_rope_kernel(
    const bf16* __restrict__ Gc, int ldc_,
    const bf16* __restrict__ Gr, int ldr_,
    bf16* __restrict__ out) {
  const int t = blockIdx.x * blockDim.x + threadIdx.x;   // NTOK*128
  const int g = t & 127, row = t >> 7;
  const int s = row & (Ss - 1);
  union { bf16x8 v; unsigned short u[8]; } vc, vr;
  vc.v = *(const bf16x8*)&Gc[(size_t)row * ldc_ + (size_t)g * 8];
  vr.v = *(const bf16x8*)&Gr[(size_t)row * ldr_ + (size_t)g * 8];
  uint4 o;
  unsigned int* op = &o.x;
#pragma unroll
  for (int qq = 0; qq < 4; ++qq) {
    const int p = g * 4 + qq;
    float c, sn;
    if (p == 0) {
      float rr = (float)s * (1.0f / 512.0f);
      c = cosf(rr); sn = sinf(rr);
    } else {
      // theta = 10000^(-2p)/512; for p>=1, r <= 4e-8 -> cosf(r)==1.0f, sinf(r)==r (fp32-exact)
      float theta = exp2f(-26.5754247590989f * (float)p) * (1.0f / 512.0f);
      sn = (float)s * theta; c = 1.0f;
    }
    float g0 = bfu2f(vr.u[2 * qq]), g1 = bfu2f(vr.u[2 * qq + 1]);
    float c0 = bfu2f(vc.u[2 * qq]), c1 = bfu2f(vc.u[2 * qq + 1]);
    op[qq] = packbf(c0 + g0 * c - g1 * sn, c1 + g1 * c + g0 * sn);
  }
  *(uint4*)&out[(size_t)row * DMODEL + (size_t)g * 8] = o;
}

// ---------------------------------------------------------------- attention v3.1
// grid (16 qt, 32 bh), 4 waves x 32 q-rows. K/V staged in LDS, dbuf, XOR-swizzled.
// Pipeline: barrier(drains stage t) -> issue stage t+1 -> compute t  (stage latency
// hides under compute; ONE barrier per kv-tile).
__global__ __launch_bounds__(256) void attn_kernel(
    const bf16* __restrict__ Qn, const bf16* __restrict__ Kn,
    const bf16* __restrict__ VT, bf16* __restrict__ AO) {
  const int qt = blockIdx.x, bh = blockIdx.y;
  const int b = bh >> 4, h = bh & 15;
  const int tid = threadIdx.x, lane = tid & 63, w = tid >> 6;
  const int q0 = qt * 128 + w * 32;
  const int l15 = lane & 15, lg = lane >> 4;
  const float INV_SCALE = 0.031008684f;   // 1/sqrt(16+512+512)

  __shared__ bf16 ldsK[2][64 * 64];   // [kv-row][d], rows 128B, XOR-swizzled
  __shared__ bf16 ldsV[2][64 * 64];   // [d-row][token], XOR-swizzled
  __shared__ bf16 ldsP[4][32 * 64];   // per-wave [q][k], XOR-swizzled

  const bf16* Kg = Kn + (size_t)(b * Ss) * DMODEL + h * 64;
  const bf16* Vg = VT + (size_t)(h * 64) * NTOK + b * Ss;

  // stage helper: linear LDS dest + inverse-swizzled global source (rule #21)
  auto stage = [&](int bs, int kv0) {
#pragma unroll
    for (int half = 0; half < 2; ++half) {
      const int c = half * 256 + tid;              // chunk 0..511 (16B each)
      const int r = c >> 3;
      const int srcb = ((c & 7) * 16) ^ ((r & 7) << 4);
      async_load16((const bf16*)((const char*)(Kg + (size_t)(kv0 + r) * DMODEL) + srcb),
                   &ldsK[bs][(half * 256 + w * 64) * 8]);
      async_load16((const bf16*)((const char*)(Vg + (size_t)r * NTOK + kv0) + srcb),
                   &ldsV[bs][(half * 256 + w * 64) * 8]);
    }
  };

  // Q B-frags: Q[q0 + i*16 + l15][d = kg*32 + lg*8 + e]
  const bf16* Qbase = Qn + (size_t)(b * Ss + q0 + l15) * DMODEL + h * 64;
  bf16x8 bq[2][2];
#pragma unroll
  for (int i = 0; i < 2; ++i)
#pragma unroll
    for (int kg = 0; kg < 2; ++kg)
      bq[i][kg] = *(const bf16x8*)&Qbase[(size_t)(i * 16) * DMODEL + kg * 32 + lg * 8];

  float m[2] = { -3.0e38f, -3.0e38f }, l[2] = { 0.f, 0.f };
  f32x4 accO[2][4] = {};

  const int kswz = (l15 & 7) << 4;          // byte XOR for K/V/P reads (row&7 == l15&7)
  char* Pw = (char*)&ldsP[w][0];

  stage(0, 0);
  for (int t = 0; t < 32; ++t) {
    const int cur = t & 1;
    __syncthreads();                         // drains vmcnt -> tile t ready; buf[cur^1] free
    if (t < 31) stage(cur ^ 1, (t + 1) * 64);  // async; drains at NEXT barrier

    const char* Kl = (const char*)&ldsK[cur][0];
    const char* Vl = (const char*)&ldsV[cur][0];

    // ---- S^T: sa[j][i] holds S[k = t*64 + j*16 + lg*4 + r][q = q0 + i*16 + l15]
    f32x4 sa[4][2] = {};
#pragma unroll
    for (int j = 0; j < 4; ++j) {
      const int row = j * 16 + l15;
      bf16x8 ak0 = *(const bf16x8*)(Kl + row * 128 + ((lg * 16) ^ kswz));
      bf16x8 ak1 = *(const bf16x8*)(Kl + row * 128 + ((64 + lg * 16) ^ kswz));
#pragma unroll
      for (int i = 0; i < 2; ++i) {
        sa[j][i] = __builtin_amdgcn_mfma_f32_16x16x32_bf16(ak0, bq[i][0], sa[j][i], 0, 0, 0);
        sa[j][i] = __builtin_amdgcn_mfma_f32_16x16x32_bf16(ak1, bq[i][1], sa[j][i], 0, 0, 0);
      }
    }

    // ---- online softmax per q-subtile; write P (wave-private, swizzled)
    float corr[2];
#pragma unroll
    for (int i = 0; i < 2; ++i) {
      float p[4][4];
      float tmax = -3.0e38f;
#pragma unroll
      for (int j = 0; j < 4; ++j)
#pragma unroll
        for (int r = 0; r < 4; ++r) {
          p[j][r] = sa[j][i][r] * INV_SCALE;
          tmax = fmaxf(tmax, p[j][r]);
        }
      tmax = fmaxf(tmax, __shfl_xor(tmax, 16, 64));
      tmax = fmaxf(tmax, __shfl_xor(tmax, 32, 64));
      float mnew = fmaxf(m[i], tmax);
      corr[i] = __expf(m[i] - mnew);
      float ts = 0.f;
#pragma unroll
      for (int j = 0; j < 4; ++j)
#pragma unroll
        for (int r = 0; r < 4; ++r) {
          p[j][r] = __expf(p[j][r] - mnew);
          ts += p[j][r];
        }
      ts += __shfl_xor(ts, 16, 64);
      ts += __shfl_xor(ts, 32, 64);
      m[i] = mnew;
      l[i] = l[i] * corr[i] + ts;
      const int q = i * 16 + l15;
#pragma unroll
      for (int j = 0; j < 4; ++j) {
        uint2 pw;
        pw.x = packbf(p[j][0], p[j][1]);
        pw.y = packbf(p[j][2], p[j][3]);
        const int chunk = (j * 2 + (lg >> 1)) ^ (q & 7);
        *(uint2*)(Pw + q * 128 + chunk * 16 + (lg & 1) * 8) = pw;
      }
    }

    // ---- rescale accO (rows q = q0 + i*16 + lg*4 + r; corr lives at lane l15 = row)
#pragma unroll
    for (int i = 0; i < 2; ++i) {
      float cr[4];
#pragma unroll
      for (int r = 0; r < 4; ++r) cr[r] = __shfl(corr[i], lg * 4 + r, 64);
#pragma unroll
      for (int dj = 0; dj < 4; ++dj)
#pragma unroll
        for (int r = 0; r < 4; ++r) accO[i][dj][r] *= cr[r];
    }

    // ---- O += P V
    bf16x8 bv[4][2];
#pragma unroll
    for (int dj = 0; dj < 4; ++dj) {
      const int vrow = dj * 16 + l15;
      bv[dj][0] = *(const bf16x8*)(Vl + vrow * 128 + ((lg * 16) ^ kswz));
      bv[dj][1] = *(const bf16x8*)(Vl + vrow * 128 + ((64 + lg * 16) ^ kswz));
    }
#pragma unroll
    for (int i = 0; i < 2; ++i) {
      const int q = i * 16 + l15;
      bf16x8 pa0 = *(const bf16x8*)(Pw + q * 128 + ((lg * 16) ^ kswz));
      bf16x8 pa1 = *(const bf16x8*)(Pw + q * 128 + ((64 + lg * 16) ^ kswz));
#pragma unroll
      for (int dj = 0; dj < 4; ++dj) {
        accO[i][dj] = __builtin_amdgcn_mfma_f32_16x16x32_bf16(pa0, bv[dj][0], accO[i][dj], 0, 0, 0);
        accO[i][dj] = __builtin_amdgcn_mfma_f32_16x16x32_bf16(pa1, bv[dj][1], accO[i][dj], 0, 0, 0);
      }
    }
  }

  // ---- epilogue
#pragma unroll
  for (int i = 0; i < 2; ++i) {
    float linv[4];
#pragma unroll
    for (int r = 0; r < 4; ++r) linv[r] = 1.0f / __shfl(l[i], lg * 4 + r, 64);
#pragma unroll
    for (int dj = 0; dj < 4; ++dj)
#pragma unroll
      for (int r = 0; r < 4; ++r)
        AO[(size_t)(b * Ss + q0 + i * 16 + lg * 4 + r) * DMODEL + h * 64 + dj * 16 + l15] =
            f2bf(accO[i][dj][r] * linv[r]);
  }
}

// ---------------------------------------------------------------- launch
extern "C" void kernel_launch(void* const* d_in, const int* in_sizes, int n_in,
                              void* d_out, int out_size, void* d_ws, size_t ws_size,
                              hipStream_t stream) {
  const float* x      = (const float*)d_in[0];
  const float* Wdq    = (const float*)d_in[1];  const float* Wdq_b  = (const float*)d_in[2];
  const float* Wuq    = (const float*)d_in[3];  const float* Wuq_b  = (const float*)d_in[4];
  const float* Wqr    = (const float*)d_in[5];  const float* Wqr_b  = (const float*)d_in[6];
  const float* Wkr    = (const float*)d_in[7];  const float* Wkr_b  = (const float*)d_in[8];
  const float* Wdkv   = (const float*)d_in[9];  const float* Wdkv_b = (const float*)d_in[10];
  const float* Wuk    = (const float*)d_in[11]; const float* Wuk_b  = (const float*)d_in[12];
  const float* Wuv    = (const float*)d_in[13]; const float* Wuv_b  = (const float*)d_in[14];
  const float* Wo     = (const float*)d_in[15]; const float* Wo_b   = (const float*)d_in[16];

  // ---- workspace (~50 MB): weights ordered for GEMM fusion adjacency ----
  char* ws = (char*)d_ws;
  size_t off = 0;
  bf16* WdqT   = (bf16*)(ws + off); off += (size_t)512  * 1024 * 2;   // down pair
  bf16* WdkvT  = (bf16*)(ws + off); off += (size_t)512  * 1024 * 2;
  bf16* WuqT   = (bf16*)(ws + off); off += (size_t)1024 * 512  * 2;   // upQ pair
  bf16* WqrT   = (bf16*)(ws + off); off += (size_t)1024 * 512  * 2;
  bf16* WukT   = (bf16*)(ws + off); off += (size_t)1024 * 512  * 2;
  bf16* WuvT   = (bf16*)(ws + off); off += (size_t)1024 * 512  * 2;
  bf16* WkrT   = (bf16*)(ws + off); off += (size_t)1024 * 1024 * 2;
  bf16* WoT    = (bf16*)(ws + off); off += (size_t)1024 * 1024 * 2;
  bf16* x_bf   = (bf16*)(ws + off); off += (size_t)NTOK * 1024 * 2;
  bf16* ct     = (bf16*)(ws + off); off += (size_t)NTOK * 1024 * 2;   // [ct_q | ct_kv]
  bf16* Ga     = (bf16*)(ws + off); off += (size_t)NTOK * 1024 * 2;
  bf16* Gb     = (bf16*)(ws + off); off += (size_t)NTOK * 1024 * 2;
  bf16* VTr    = (bf16*)(ws + off); off += (size_t)NTOK * 1024 * 2;
  bf16* Gq     = Ga;                                  // fused upQ output spans Ga+Gb
  bf16* Qn     = (bf16*)d_out;                        // dead before final GEMM
  bf16* Kn     = (bf16*)d_out + (size_t)NTOK * DMODEL;
  bf16* AO     = Ga;
  (void)ws_size; (void)in_sizes; (void)n_in; (void)out_size;

  TransPack tp = {{
    { Wdq,  WdqT,  1024, 512,  0    },
    { Wdkv, WdkvT, 1024, 512,  128  },
    { Wuq,  WuqT,  512,  1024, 256  },
    { Wqr,  WqrT,  512,  1024, 384  },
    { Wuk,  WukT,  512,  1024, 512  },
    { Wuv,  WuvT,  512,  1024, 640  },
    { Wkr,  WkrT,  1024, 1024, 768  },
    { Wo,   WoT,   1024, 1024, 1024 },
  }};
  transpose8_kernel<<<1280, 256, 0, stream>>>(tp);
  convert_kernel<<<(NTOK * DMODEL / 4 + 255) / 256, 256, 0, stream>>>(x, x_bf, NTOK * DMODEL / 4);

  // fused down-projection: ct = x @ [Wdq|Wdkv]  (N=1024, K=1024)
  gemm_kernel<0, 0><<<dim3(8, 32), 256, 0, stream>>>(
      x_bf, 1024, WdqT, 1024, Wdq_b, Wdkv_b, 512, ct, 1024, 1024);

  // fused up-Q: Gq = ct_q @ [Wuq|Wqr]  (N=2048, K=512)
  gemm_kernel<0, 0><<<dim3(16, 32), 256, 0, stream>>>(
      ct, 1024, WuqT, 512, Wuq_b, Wqr_b, 1024, Gq, 2048, 512);
  combine_rope_kernel<<<NTOK * 128 / 256, 256, 0, stream>>>(Gq, 2048, Gq + 1024, 2048, Qn);

  // V^T directly: VT[d][tok] = Wuv^T @ ct_kv^T  (M=1024, N=4096, K=512)
  gemm_kernel<0, 1><<<dim3(32, 8), 256, 0, stream>>>(
      WuvT, 512, ct + 512, 1024, Wuv_b, Wuv_b, NTOK, VTr, NTOK, 512);

  // key = up(ct_kv) + rope(kr(x))
  gemm_kernel<0, 0><<<dim3(8, 32), 256, 0, stream>>>(
      ct + 512, 1024, WukT, 512, Wuk_b, Wuk_b, 1024, Ga, 1024, 512);
  gemm_kernel<0, 0><<<dim3(8, 32), 256, 0, stream>>>(
      x_bf, 1024, WkrT, 1024, Wkr_b, Wkr_b, 1024, Gb, 1024, 1024);
  combine_rope_kernel<<<NTOK * 128 / 256, 256, 0, stream>>>(Ga, 1024, Gb, 1024, Kn);

  // attention
  attn_kernel<<<dim3(16, 32), 256, 0, stream>>>(Qn, Kn, VTr, AO);

  // output projection (fp32 out)
  gemm_kernel<1, 0><<<dim3(8, 32), 256, 0, stream>>>(
      AO, 1024, WoT, 1024, Wo_b, Wo_b, 1024, (float*)d_out, 1024, 1024);
}

// Round 8
// 218.311 us; speedup vs baseline: 2.1879x; 1.0939x over previous
//
#include <hip/hip_runtime.h>
#include <hip/hip_bf16.h>
#include <math.h>
#include <limits.h>

typedef __hip_bfloat16 bf16;
typedef __bf16 bf16x8 __attribute__((ext_vector_type(8)));
typedef float  f32x4  __attribute__((ext_vector_type(4)));

#define DEVI __device__ __forceinline__

static constexpr int Bb     = 2;
static constexpr int Ss     = 2048;
static constexpr int DMODEL = 1024;
static constexpr int NTOK   = Bb * Ss;   // 4096

DEVI float bf2f(bf16 v) { return __bfloat162float(v); }
DEVI bf16  f2bf(float v) { return __float2bfloat16(v); }

DEVI unsigned int packbf(float lo, float hi) {
  union { bf16 b; unsigned short u; } a, c;
  a.b = f2bf(lo); c.b = f2bf(hi);
  return ((unsigned int)c.u << 16) | a.u;
}
DEVI float bfu2f(unsigned short u) {
  unsigned int x = (unsigned int)u << 16;
  float f; __builtin_memcpy(&f, &x, 4); return f;
}

DEVI void async_load16(const bf16* g, bf16* l) {
  __builtin_amdgcn_global_load_lds((const __attribute__((address_space(1))) void*)g,
                                   (__attribute__((address_space(3))) void*)l, 16, 0, 0);
}

// ---------------------------------------------------------------- fp32 -> bf16 convert
__global__ __launch_bounds__(256) void convert_kernel(
    const float* __restrict__ in, bf16* __restrict__ out, int n4) {
  const int t = blockIdx.x * blockDim.x + threadIdx.x;
  if (t >= n4) return;
  const float4 v = ((const float4*)in)[t];
  uint2 o; o.x = packbf(v.x, v.y); o.y = packbf(v.z, v.w);
  *(uint2*)&out[(size_t)t * 4] = o;
}

// ---------------------------------------------------------------- fused weight transpose
struct TransDesc { const float* src; bf16* dst; int R; int C; int tstart; };
struct TransPack { TransDesc d[8]; };

__global__ __launch_bounds__(256) void transpose8_kernel(TransPack p) {
  const int t = blockIdx.x;
  int i = 0;
#pragma unroll
  for (int j = 1; j < 8; ++j) if (t >= p.d[j].tstart) i = j;
  const float* __restrict__ in = p.d[i].src;
  bf16* __restrict__ out = p.d[i].dst;
  const int R = p.d[i].R, C = p.d[i].C;
  const int rel = t - p.d[i].tstart;
  const int tilesC = C >> 6;
  const int r0 = (rel / tilesC) * 64, c0 = (rel % tilesC) * 64;

  __shared__ bf16 tl[64][65];
  const int tc = threadIdx.x & 63, tr = threadIdx.x >> 6;
#pragma unroll
  for (int q = 0; q < 16; ++q) {
    int r = tr + q * 4;
    tl[r][tc] = f2bf(in[(size_t)(r0 + r) * C + c0 + tc]);
  }
  __syncthreads();
#pragma unroll
  for (int q = 0; q < 16; ++q) {
    int r = tr + q * 4;
    out[(size_t)(c0 + r) * R + r0 + tc] = tl[tc][r];
  }
}

// ---------------------------------------------------------------- batched GEMM
// Several independent C = A@WT^T + bias GEMMs in one dispatch (block-range decode).
struct GemmDesc {
  const bf16* A; const bf16* WT; const float* b1; const float* b2; bf16* C;
  int lda, ldb, ldc, K, bsplit, nTX, blkStart, biasRow;
};
struct GemmBatch { GemmDesc d[4]; };

__global__ __launch_bounds__(256) void gemm_batch_kernel(GemmBatch gb) {
  const int t = blockIdx.x;
  int di = 0;
#pragma unroll
  for (int j = 1; j < 4; ++j) if (t >= gb.d[j].blkStart) di = j;
  const GemmDesc D = gb.d[di];
  const int rel = t - D.blkStart;
  const int tileN = (rel % D.nTX) * 128;
  const int tileM = (rel / D.nTX) * 128;

  __shared__ bf16 ldsA[128 * 32];
  __shared__ bf16 ldsB[128 * 32];
  const int tid = threadIdx.x;
  const int lane = tid & 63;
  const int w = tid >> 6;
  const int wr = w >> 1, wc = w & 1;
  const int l15 = lane & 15, lg = lane >> 4;
  const int lrow = lane >> 2;
  const int lcol = (lane & 3) * 8;

  f32x4 acc[4][4] = {};

  for (int k0 = 0; k0 < D.K; k0 += 32) {
    async_load16(D.A  + (size_t)(tileM + w * 32 +      lrow) * D.lda + k0 + lcol, &ldsA[(w * 32) * 32]);
    async_load16(D.A  + (size_t)(tileM + w * 32 + 16 + lrow) * D.lda + k0 + lcol, &ldsA[(w * 32 + 16) * 32]);
    async_load16(D.WT + (size_t)(tileN + w * 32 +      lrow) * D.ldb + k0 + lcol, &ldsB[(w * 32) * 32]);
    async_load16(D.WT + (size_t)(tileN + w * 32 + 16 + lrow) * D.ldb + k0 + lcol, &ldsB[(w * 32 + 16) * 32]);
    __syncthreads();

    bf16x8 af[4], bfr[4];
#pragma unroll
    for (int i = 0; i < 4; ++i) {
      af[i]  = *(const bf16x8*)&ldsA[(wr * 64 + i * 16 + l15) * 32 + lg * 8];
      bfr[i] = *(const bf16x8*)&ldsB[(wc * 64 + i * 16 + l15) * 32 + lg * 8];
    }
#pragma unroll
    for (int i = 0; i < 4; ++i)
#pragma unroll
      for (int j = 0; j < 4; ++j)
        acc[i][j] = __builtin_amdgcn_mfma_f32_16x16x32_bf16(af[i], bfr[j], acc[i][j], 0, 0, 0);
    __syncthreads();
  }

  const int mbase = tileM + wr * 64;
  const int nbase = tileN + wc * 64;
#pragma unroll
  for (int j = 0; j < 4; ++j) {
    int col = nbase + j * 16 + l15;
    float bvc = D.biasRow ? 0.0f : (col < D.bsplit ? D.b1[col] : D.b2[col - D.bsplit]);
#pragma unroll
    for (int i = 0; i < 4; ++i)
#pragma unroll
      for (int r = 0; r < 4; ++r) {
        int row = mbase + i * 16 + lg * 4 + r;
        float bv = D.biasRow ? D.b1[row] : bvc;
        D.C[(size_t)row * D.ldc + col] = f2bf(acc[i][j][r] + bv);
      }
  }
}

// ---------------------------------------------------------------- GEMM (fp32-out, for outproj)
__global__ __launch_bounds__(256) void gemm_kernel_f32(
    const bf16* __restrict__ A, int lda,
    const bf16* __restrict__ WT, int ldb,
    const float* __restrict__ b1,
    float* __restrict__ Cout, int ldc, int K) {
  __shared__ bf16 ldsA[128 * 32];
  __shared__ bf16 ldsB[128 * 32];
  const int tid = threadIdx.x;
  const int lane = tid & 63;
  const int w = tid >> 6;
  const int wr = w >> 1, wc = w & 1;
  const int tileM = blockIdx.y * 128;
  const int tileN = blockIdx.x * 128;
  const int l15 = lane & 15, lg = lane >> 4;
  const int lrow = lane >> 2;
  const int lcol = (lane & 3) * 8;

  f32x4 acc[4][4] = {};

  for (int k0 = 0; k0 < K; k0 += 32) {
    async_load16(A  + (size_t)(tileM + w * 32 +      lrow) * lda + k0 + lcol, &ldsA[(w * 32) * 32]);
    async_load16(A  + (size_t)(tileM + w * 32 + 16 + lrow) * lda + k0 + lcol, &ldsA[(w * 32 + 16) * 32]);
    async_load16(WT + (size_t)(tileN + w * 32 +      lrow) * ldb + k0 + lcol, &ldsB[(w * 32) * 32]);
    async_load16(WT + (size_t)(tileN + w * 32 + 16 + lrow) * ldb + k0 + lcol, &ldsB[(w * 32 + 16) * 32]);
    __syncthreads();

    bf16x8 af[4], bfr[4];
#pragma unroll
    for (int i = 0; i < 4; ++i) {
      af[i]  = *(const bf16x8*)&ldsA[(wr * 64 + i * 16 + l15) * 32 + lg * 8];
      bfr[i] = *(const bf16x8*)&ldsB[(wc * 64 + i * 16 + l15) * 32 + lg * 8];
    }
#pragma unroll
    for (int i = 0; i < 4; ++i)
#pragma unroll
      for (int j = 0; j < 4; ++j)
        acc[i][j] = __builtin_amdgcn_mfma_f32_16x16x32_bf16(af[i], bfr[j], acc[i][j], 0, 0, 0);
    __syncthreads();
  }

  const int mbase = tileM + wr * 64;
  const int nbase = tileN + wc * 64;
#pragma unroll
  for (int j = 0; j < 4; ++j) {
    int col = nbase + j * 16 + l15;
    float bvc = b1[col];
#pragma unroll
    for (int i = 0; i < 4; ++i)
#pragma unroll
      for (int r = 0; r < 4; ++r) {
        int row = mbase + i * 16 + lg * 4 + r;
        Cout[(size_t)row * ldc + col] = acc[i][j][r] + bvc;
      }
  }
}

// ---------------------------------------------------------------- combine + rope (in-place-safe)
__global__ __launch_bounds__(256) void combine_rope_kernel(
    const bf16* __restrict__ Gc, int ldc_,
    const bf16* __restrict__ Gr, int ldr_,
    bf16* __restrict__ out) {
  const int t = blockIdx.x * blockDim.x + threadIdx.x;   // NTOK*128
  const int g = t & 127, row = t >> 7;
  const int s = row & (Ss - 1);
  union { bf16x8 v; unsigned short u[8]; } vc, vr;
  vc.v = *(const bf16x8*)&Gc[(size_t)row * ldc_ + (size_t)g * 8];
  vr.v = *(const bf16x8*)&Gr[(size_t)row * ldr_ + (size_t)g * 8];
  uint4 o;
  unsigned int* op = &o.x;
#pragma unroll
  for (int qq = 0; qq < 4; ++qq) {
    const int p = g * 4 + qq;
    float c, sn;
    if (p == 0) {
      float rr = (float)s * (1.0f / 512.0f);
      c = cosf(rr); sn = sinf(rr);
    } else {
      // theta = 10000^(-2p)/512; for p>=1, r <= 4e-8 -> cosf(r)==1.0f, sinf(r)==r (fp32-exact)
      float theta = exp2f(-26.5754247590989f * (float)p) * (1.0f / 512.0f);
      sn = (float)s * theta; c = 1.0f;
    }
    float g0 = bfu2f(vr.u[2 * qq]), g1 = bfu2f(vr.u[2 * qq + 1]);
    float c0 = bfu2f(vc.u[2 * qq]), c1 = bfu2f(vc.u[2 * qq + 1]);
    op[qq] = packbf(c0 + g0 * c - g1 * sn, c1 + g1 * c + g0 * sn);
  }
  *(uint4*)&out[(size_t)row * DMODEL + (size_t)g * 8] = o;
}

// ---------------------------------------------------------------- attention v4
// grid (32 qt, 32 bh), 4 waves x 16 q-rows -> 1024 blocks = 4 blocks/CU.
// K/V LDS dbuf (XOR-swizzled, pre-swizzled source). exp2-domain softmax + defer-max.
__global__ __launch_bounds__(256) void attn_kernel(
    const bf16* __restrict__ Qn, const bf16* __restrict__ Kn,
    const bf16* __restrict__ VT, bf16* __restrict__ AO) {
  const int qt = blockIdx.x, bh = blockIdx.y;
  const int b = bh >> 4, h = bh & 15;
  const int tid = threadIdx.x, lane = tid & 63, w = tid >> 6;
  const int q0 = qt * 64 + w * 16;
  const int l15 = lane & 15, lg = lane >> 4;
  const float SC2 = 0.044736075f;    // (1/sqrt(1040)) * log2(e)
  const float THR = 11.5415603f;     // 8 * log2(e)

  __shared__ bf16 ldsK[2][64 * 64];  // 16 KB
  __shared__ bf16 ldsV[2][64 * 64];  // 16 KB
  __shared__ bf16 ldsP[4][16 * 64];  // 8 KB, per-wave

  const bf16* Kg = Kn + (size_t)(b * Ss) * DMODEL + h * 64;
  const bf16* Vg = VT + (size_t)(h * 64) * NTOK + b * Ss;

  auto stage = [&](int bs, int kv0) {
#pragma unroll
    for (int half = 0; half < 2; ++half) {
      const int c = half * 256 + tid;              // chunk 0..511 (16B each)
      const int r = c >> 3;
      const int srcb = ((c & 7) * 16) ^ ((r & 7) << 4);
      async_load16((const bf16*)((const char*)(Kg + (size_t)(kv0 + r) * DMODEL) + srcb),
                   &ldsK[bs][(half * 256 + w * 64) * 8]);
      async_load16((const bf16*)((const char*)(Vg + (size_t)r * NTOK + kv0) + srcb),
                   &ldsV[bs][(half * 256 + w * 64) * 8]);
    }
  };

  // Q B-frag: Q[q0 + l15][d = kg*32 + lg*8 + e]
  const bf16* Qbase = Qn + (size_t)(b * Ss + q0 + l15) * DMODEL + h * 64;
  bf16x8 bq0 = *(const bf16x8*)&Qbase[lg * 8];
  bf16x8 bq1 = *(const bf16x8*)&Qbase[32 + lg * 8];

  float m = -3.0e38f, l = 0.0f;
  f32x4 accO[4] = {};
  const int kswz = (l15 & 7) << 4;
  char* Pw = (char*)&ldsP[w][0];

  stage(0, 0);
  for (int t = 0; t < 32; ++t) {
    const int cur = t & 1;
    __syncthreads();                           // tile t ready; buf[cur^1] free
    if (t < 31) stage(cur ^ 1, (t + 1) * 64);  // drains at next barrier

    const char* Kl = (const char*)&ldsK[cur][0];
    const char* Vl = (const char*)&ldsV[cur][0];

    // ---- S^T: sa[j] lane holds S[k = t*64 + j*16 + lg*4 + r][q = q0 + l15] (x SC2 later)
    f32x4 sa[4] = {};
#pragma unroll
    for (int j = 0; j < 4; ++j) {
      const int row = j * 16 + l15;
      bf16x8 ak0 = *(const bf16x8*)(Kl + row * 128 + ((lg * 16) ^ kswz));
      bf16x8 ak1 = *(const bf16x8*)(Kl + row * 128 + ((64 + lg * 16) ^ kswz));
      sa[j] = __builtin_amdgcn_mfma_f32_16x16x32_bf16(ak0, bq0, sa[j], 0, 0, 0);
      sa[j] = __builtin_amdgcn_mfma_f32_16x16x32_bf16(ak1, bq1, sa[j], 0, 0, 0);
    }

    // ---- exp2-domain online softmax for q-row q0+l15
    float v[4][4];
    float pmax = -3.0e38f;
#pragma unroll
    for (int j = 0; j < 4; ++j)
#pragma unroll
      for (int r = 0; r < 4; ++r) {
        v[j][r] = sa[j][r] * SC2;
        pmax = fmaxf(pmax, v[j][r]);
      }
    pmax = fmaxf(pmax, __shfl_xor(pmax, 16, 64));
    pmax = fmaxf(pmax, __shfl_xor(pmax, 32, 64));
    if (__any(pmax - m > THR)) {               // defer-max: rescale only on real growth
      float mnew = fmaxf(m, pmax);
      float corr = exp2f(m - mnew);
      m = mnew;
      l *= corr;
      float cr[4];
#pragma unroll
      for (int r = 0; r < 4; ++r) cr[r] = __shfl(corr, lg * 4 + r, 64);
#pragma unroll
      for (int dj = 0; dj < 4; ++dj)
#pragma unroll
        for (int r = 0; r < 4; ++r) accO[dj][r] *= cr[r];
    }
    float p[4][4];
    float ts = 0.f;
#pragma unroll
    for (int j = 0; j < 4; ++j)
#pragma unroll
      for (int r = 0; r < 4; ++r) {
        p[j][r] = exp2f(v[j][r] - m);
        ts += p[j][r];
      }
    ts += __shfl_xor(ts, 16, 64);
    ts += __shfl_xor(ts, 32, 64);
    l += ts;

    // ---- write P (wave-private, swizzled), q = l15
    const int q = l15;
#pragma unroll
    for (int j = 0; j < 4; ++j) {
      uint2 pw;
      pw.x = packbf(p[j][0], p[j][1]);
      pw.y = packbf(p[j][2], p[j][3]);
      const int chunk = (j * 2 + (lg >> 1)) ^ (q & 7);
      *(uint2*)(Pw + q * 128 + chunk * 16 + (lg & 1) * 8) = pw;
    }

    // ---- O += P V
    bf16x8 bv[4][2];
#pragma unroll
    for (int dj = 0; dj < 4; ++dj) {
      const int vrow = dj * 16 + l15;
      bv[dj][0] = *(const bf16x8*)(Vl + vrow * 128 + ((lg * 16) ^ kswz));
      bv[dj][1] = *(const bf16x8*)(Vl + vrow * 128 + ((64 + lg * 16) ^ kswz));
    }
    bf16x8 pa0 = *(const bf16x8*)(Pw + q * 128 + ((lg * 16) ^ kswz));
    bf16x8 pa1 = *(const bf16x8*)(Pw + q * 128 + ((64 + lg * 16) ^ kswz));
#pragma unroll
    for (int dj = 0; dj < 4; ++dj) {
      accO[dj] = __builtin_amdgcn_mfma_f32_16x16x32_bf16(pa0, bv[dj][0], accO[dj], 0, 0, 0);
      accO[dj] = __builtin_amdgcn_mfma_f32_16x16x32_bf16(pa1, bv[dj][1], accO[dj], 0, 0, 0);
    }
  }

  // ---- epilogue: O[q0 + lg*4 + r][dj*16 + l15]
  float linv[4];
#pragma unroll
  for (int r = 0; r < 4; ++r) linv[r] = 1.0f / __shfl(l, lg * 4 + r, 64);
#pragma unroll
  for (int dj = 0; dj < 4; ++dj)
#pragma unroll
    for (int r = 0; r < 4; ++r)
      AO[(size_t)(b * Ss + q0 + lg * 4 + r) * DMODEL + h * 64 + dj * 16 + l15] =
          f2bf(accO[dj][r] * linv[r]);
}

// ---------------------------------------------------------------- launch
extern "C" void kernel_launch(void* const* d_in, const int* in_sizes, int n_in,
                              void* d_out, int out_size, void* d_ws, size_t ws_size,
                              hipStream_t stream) {
  const float* x      = (const float*)d_in[0];
  const float* Wdq    = (const float*)d_in[1];  const float* Wdq_b  = (const float*)d_in[2];
  const float* Wuq    = (const float*)d_in[3];  const float* Wuq_b  = (const float*)d_in[4];
  const float* Wqr    = (const float*)d_in[5];  const float* Wqr_b  = (const float*)d_in[6];
  const float* Wkr    = (const float*)d_in[7];  const float* Wkr_b  = (const float*)d_in[8];
  const float* Wdkv   = (const float*)d_in[9];  const float* Wdkv_b = (const float*)d_in[10];
  const float* Wuk    = (const float*)d_in[11]; const float* Wuk_b  = (const float*)d_in[12];
  const float* Wuv    = (const float*)d_in[13]; const float* Wuv_b  = (const float*)d_in[14];
  const float* Wo     = (const float*)d_in[15]; const float* Wo_b   = (const float*)d_in[16];

  // ---- workspace (~42 MB) ----
  char* ws = (char*)d_ws;
  size_t off = 0;
  bf16* WdqT   = (bf16*)(ws + off); off += (size_t)512  * 1024 * 2;   // down pair (adjacent)
  bf16* WdkvT  = (bf16*)(ws + off); off += (size_t)512  * 1024 * 2;
  bf16* WuqT   = (bf16*)(ws + off); off += (size_t)1024 * 512  * 2;
  bf16* WqrT   = (bf16*)(ws + off); off += (size_t)1024 * 512  * 2;
  bf16* WukT   = (bf16*)(ws + off); off += (size_t)1024 * 512  * 2;
  bf16* WuvT   = (bf16*)(ws + off); off += (size_t)1024 * 512  * 2;
  bf16* WkrT   = (bf16*)(ws + off); off += (size_t)1024 * 1024 * 2;
  bf16* WoT    = (bf16*)(ws + off); off += (size_t)1024 * 1024 * 2;
  bf16* x_bf   = (bf16*)(ws + off); off += (size_t)NTOK * 1024 * 2;   // reused as Gupk
  bf16* ct     = (bf16*)(ws + off); off += (size_t)NTOK * 1024 * 2;   // [ct_q | ct_kv]
  bf16* Ga     = (bf16*)(ws + off); off += (size_t)NTOK * 1024 * 2;   // upQc, later AO
  bf16* VTr    = (bf16*)(ws + off); off += (size_t)NTOK * 1024 * 2;
  bf16* Gupk   = x_bf;                                 // x_bf dead after batch A
  bf16* Qn     = (bf16*)d_out;                         // dead before final GEMM
  bf16* Kn     = (bf16*)d_out + (size_t)NTOK * DMODEL;
  bf16* AO     = Ga;
  (void)ws_size; (void)in_sizes; (void)n_in; (void)out_size;

  TransPack tp = {{
    { Wdq,  WdqT,  1024, 512,  0    },
    { Wdkv, WdkvT, 1024, 512,  128  },
    { Wuq,  WuqT,  512,  1024, 256  },
    { Wqr,  WqrT,  512,  1024, 384  },
    { Wuk,  WukT,  512,  1024, 512  },
    { Wuv,  WuvT,  512,  1024, 640  },
    { Wkr,  WkrT,  1024, 1024, 768  },
    { Wo,   WoT,   1024, 1024, 1024 },
  }};
  transpose8_kernel<<<1280, 256, 0, stream>>>(tp);
  convert_kernel<<<(NTOK * DMODEL / 4 + 255) / 256, 256, 0, stream>>>(x, x_bf, NTOK * DMODEL / 4);

  // ---- batch A (512 blocks): down = x@[Wdq|Wdkv] -> ct ; Kr = x@Wkr -> Kn region ----
  GemmBatch ba = {{
    { x_bf, WdqT, Wdq_b, Wdkv_b, ct, 1024, 1024, 1024, 1024, 512,     8, 0,       0 },
    { x_bf, WkrT, Wkr_b, Wkr_b,  Kn, 1024, 1024, 1024, 1024, INT_MAX, 8, 256,     0 },
    { 0, 0, 0, 0, 0, 0, 0, 0, 0, 0, 1, INT_MAX, 0 },
    { 0, 0, 0, 0, 0, 0, 0, 0, 0, 0, 1, INT_MAX, 0 },
  }};
  gemm_batch_kernel<<<512, 256, 0, stream>>>(ba);

  // ---- batch B (1024 blocks): upQc->Ga ; upQr->Qn ; upK->Gupk ; V^T->VTr ----
  GemmBatch bb = {{
    { ct,       WuqT,     Wuq_b, Wuq_b, Ga,   1024, 512,  1024, 512, INT_MAX, 8,  0,   0 },
    { ct,       WqrT,     Wqr_b, Wqr_b, Qn,   1024, 512,  1024, 512, INT_MAX, 8,  256, 0 },
    { ct + 512, WukT,     Wuk_b, Wuk_b, Gupk, 1024, 512,  1024, 512, INT_MAX, 8,  512, 0 },
    { WuvT,     ct + 512, Wuv_b, Wuv_b, VTr,  512,  1024, NTOK, 512, INT_MAX, 32, 768, 1 },
  }};
  gemm_batch_kernel<<<1024, 256, 0, stream>>>(bb);

  // combines (in place on the rope operand)
  combine_rope_kernel<<<NTOK * 128 / 256, 256, 0, stream>>>(Ga, 1024, Qn, 1024, Qn);
  combine_rope_kernel<<<NTOK * 128 / 256, 256, 0, stream>>>(Gupk, 1024, Kn, 1024, Kn);

  // attention
  attn_kernel<<<dim3(32, 32), 256, 0, stream>>>(Qn, Kn, VTr, AO);

  // output projection (fp32 out)
  gemm_kernel_f32<<<dim3(8, 32), 256, 0, stream>>>(
      AO, 1024, WoT, 1024, Wo_b, (float*)d_out, 1024, 1024);
}

// Round 9
// 197.369 us; speedup vs baseline: 2.4201x; 1.1061x over previous
//
#include <hip/hip_runtime.h>
#include <hip/hip_bf16.h>
#include <math.h>
#include <limits.h>

typedef __hip_bfloat16 bf16;
typedef __bf16 bf16x8 __attribute__((ext_vector_type(8)));
typedef float  f32x4  __attribute__((ext_vector_type(4)));

#define DEVI __device__ __forceinline__

static constexpr int Bb     = 2;
static constexpr int Ss     = 2048;
static constexpr int DMODEL = 1024;
static constexpr int NTOK   = Bb * Ss;   // 4096

DEVI float bf2f(bf16 v) { return __bfloat162float(v); }
DEVI bf16  f2bf(float v) { return __float2bfloat16(v); }

DEVI unsigned int packbf(float lo, float hi) {
  union { bf16 b; unsigned short u; } a, c;
  a.b = f2bf(lo); c.b = f2bf(hi);
  return ((unsigned int)c.u << 16) | a.u;
}
DEVI float bfu2f(unsigned short u) {
  unsigned int x = (unsigned int)u << 16;
  float f; __builtin_memcpy(&f, &x, 4); return f;
}

DEVI void async_load16(const bf16* g, bf16* l) {
  __builtin_amdgcn_global_load_lds((const __attribute__((address_space(1))) void*)g,
                                   (__attribute__((address_space(3))) void*)l, 16, 0, 0);
}

// ---------------------------------------------------------------- fp32 -> bf16 convert
__global__ __launch_bounds__(256) void convert_kernel(
    const float* __restrict__ in, bf16* __restrict__ out, int n4) {
  const int t = blockIdx.x * blockDim.x + threadIdx.x;
  if (t >= n4) return;
  const float4 v = ((const float4*)in)[t];
  uint2 o; o.x = packbf(v.x, v.y); o.y = packbf(v.z, v.w);
  *(uint2*)&out[(size_t)t * 4] = o;
}

// ---------------------------------------------------------------- fused weight transpose
struct TransDesc { const float* src; bf16* dst; int R; int C; int tstart; };
struct TransPack { TransDesc d[8]; };

__global__ __launch_bounds__(256) void transpose8_kernel(TransPack p) {
  const int t = blockIdx.x;
  int i = 0;
#pragma unroll
  for (int j = 1; j < 8; ++j) if (t >= p.d[j].tstart) i = j;
  const float* __restrict__ in = p.d[i].src;
  bf16* __restrict__ out = p.d[i].dst;
  const int R = p.d[i].R, C = p.d[i].C;
  const int rel = t - p.d[i].tstart;
  const int tilesC = C >> 6;
  const int r0 = (rel / tilesC) * 64, c0 = (rel % tilesC) * 64;

  __shared__ bf16 tl[64][65];
  const int tc = threadIdx.x & 63, tr = threadIdx.x >> 6;
#pragma unroll
  for (int q = 0; q < 16; ++q) {
    int r = tr + q * 4;
    tl[r][tc] = f2bf(in[(size_t)(r0 + r) * C + c0 + tc]);
  }
  __syncthreads();
#pragma unroll
  for (int q = 0; q < 16; ++q) {
    int r = tr + q * 4;
    out[(size_t)(c0 + r) * R + r0 + tc] = tl[tc][r];
  }
}

// ---------------------------------------------------------------- batched GEMM
struct GemmDesc {
  const bf16* A; const bf16* WT; const float* b1; const float* b2; bf16* C;
  int lda, ldb, ldc, K, bsplit, nTX, blkStart, biasRow;
};
struct GemmBatch { GemmDesc d[4]; };

__global__ __launch_bounds__(256) void gemm_batch_kernel(GemmBatch gb) {
  const int t = blockIdx.x;
  int di = 0;
#pragma unroll
  for (int j = 1; j < 4; ++j) if (t >= gb.d[j].blkStart) di = j;
  const GemmDesc D = gb.d[di];
  const int rel = t - D.blkStart;
  const int tileN = (rel % D.nTX) * 128;
  const int tileM = (rel / D.nTX) * 128;

  __shared__ bf16 ldsA[128 * 32];
  __shared__ bf16 ldsB[128 * 32];
  const int tid = threadIdx.x;
  const int lane = tid & 63;
  const int w = tid >> 6;
  const int wr = w >> 1, wc = w & 1;
  const int l15 = lane & 15, lg = lane >> 4;
  const int lrow = lane >> 2;
  const int lcol = (lane & 3) * 8;

  f32x4 acc[4][4] = {};

  for (int k0 = 0; k0 < D.K; k0 += 32) {
    async_load16(D.A  + (size_t)(tileM + w * 32 +      lrow) * D.lda + k0 + lcol, &ldsA[(w * 32) * 32]);
    async_load16(D.A  + (size_t)(tileM + w * 32 + 16 + lrow) * D.lda + k0 + lcol, &ldsA[(w * 32 + 16) * 32]);
    async_load16(D.WT + (size_t)(tileN + w * 32 +      lrow) * D.ldb + k0 + lcol, &ldsB[(w * 32) * 32]);
    async_load16(D.WT + (size_t)(tileN + w * 32 + 16 + lrow) * D.ldb + k0 + lcol, &ldsB[(w * 32 + 16) * 32]);
    __syncthreads();

    bf16x8 af[4], bfr[4];
#pragma unroll
    for (int i = 0; i < 4; ++i) {
      af[i]  = *(const bf16x8*)&ldsA[(wr * 64 + i * 16 + l15) * 32 + lg * 8];
      bfr[i] = *(const bf16x8*)&ldsB[(wc * 64 + i * 16 + l15) * 32 + lg * 8];
    }
#pragma unroll
    for (int i = 0; i < 4; ++i)
#pragma unroll
      for (int j = 0; j < 4; ++j)
        acc[i][j] = __builtin_amdgcn_mfma_f32_16x16x32_bf16(af[i], bfr[j], acc[i][j], 0, 0, 0);
    __syncthreads();
  }

  const int mbase = tileM + wr * 64;
  const int nbase = tileN + wc * 64;
#pragma unroll
  for (int j = 0; j < 4; ++j) {
    int col = nbase + j * 16 + l15;
    float bvc = D.biasRow ? 0.0f : (col < D.bsplit ? D.b1[col] : D.b2[col - D.bsplit]);
#pragma unroll
    for (int i = 0; i < 4; ++i)
#pragma unroll
      for (int r = 0; r < 4; ++r) {
        int row = mbase + i * 16 + lg * 4 + r;
        float bv = D.biasRow ? D.b1[row] : bvc;
        D.C[(size_t)row * D.ldc + col] = f2bf(acc[i][j][r] + bv);
      }
  }
}

// ---------------------------------------------------------------- GEMM (fp32-out, for outproj)
__global__ __launch_bounds__(256) void gemm_kernel_f32(
    const bf16* __restrict__ A, int lda,
    const bf16* __restrict__ WT, int ldb,
    const float* __restrict__ b1,
    float* __restrict__ Cout, int ldc, int K) {
  __shared__ bf16 ldsA[128 * 32];
  __shared__ bf16 ldsB[128 * 32];
  const int tid = threadIdx.x;
  const int lane = tid & 63;
  const int w = tid >> 6;
  const int wr = w >> 1, wc = w & 1;
  const int tileM = blockIdx.y * 128;
  const int tileN = blockIdx.x * 128;
  const int l15 = lane & 15, lg = lane >> 4;
  const int lrow = lane >> 2;
  const int lcol = (lane & 3) * 8;

  f32x4 acc[4][4] = {};

  for (int k0 = 0; k0 < K; k0 += 32) {
    async_load16(A  + (size_t)(tileM + w * 32 +      lrow) * lda + k0 + lcol, &ldsA[(w * 32) * 32]);
    async_load16(A  + (size_t)(tileM + w * 32 + 16 + lrow) * lda + k0 + lcol, &ldsA[(w * 32 + 16) * 32]);
    async_load16(WT + (size_t)(tileN + w * 32 +      lrow) * ldb + k0 + lcol, &ldsB[(w * 32) * 32]);
    async_load16(WT + (size_t)(tileN + w * 32 + 16 + lrow) * ldb + k0 + lcol, &ldsB[(w * 32 + 16) * 32]);
    __syncthreads();

    bf16x8 af[4], bfr[4];
#pragma unroll
    for (int i = 0; i < 4; ++i) {
      af[i]  = *(const bf16x8*)&ldsA[(wr * 64 + i * 16 + l15) * 32 + lg * 8];
      bfr[i] = *(const bf16x8*)&ldsB[(wc * 64 + i * 16 + l15) * 32 + lg * 8];
    }
#pragma unroll
    for (int i = 0; i < 4; ++i)
#pragma unroll
      for (int j = 0; j < 4; ++j)
        acc[i][j] = __builtin_amdgcn_mfma_f32_16x16x32_bf16(af[i], bfr[j], acc[i][j], 0, 0, 0);
    __syncthreads();
  }

  const int mbase = tileM + wr * 64;
  const int nbase = tileN + wc * 64;
#pragma unroll
  for (int j = 0; j < 4; ++j) {
    int col = nbase + j * 16 + l15;
    float bvc = b1[col];
#pragma unroll
    for (int i = 0; i < 4; ++i)
#pragma unroll
      for (int r = 0; r < 4; ++r) {
        int row = mbase + i * 16 + lg * 4 + r;
        Cout[(size_t)row * ldc + col] = acc[i][j][r] + bvc;
      }
  }
}

// ---------------------------------------------------------------- combine + rope
__global__ __launch_bounds__(256) void combine_rope_kernel(
    const bf16* __restrict__ Gc, int ldc_,
    const bf16* __restrict__ Gr, int ldr_,
    bf16* __restrict__ out) {
  const int t = blockIdx.x * blockDim.x + threadIdx.x;   // NTOK*128
  const int g = t & 127, row = t >> 7;
  const int s = row & (Ss - 1);
  union { bf16x8 v; unsigned short u[8]; } vc, vr;
  vc.v = *(const bf16x8*)&Gc[(size_t)row * ldc_ + (size_t)g * 8];
  vr.v = *(const bf16x8*)&Gr[(size_t)row * ldr_ + (size_t)g * 8];
  uint4 o;
  unsigned int* op = &o.x;
#pragma unroll
  for (int qq = 0; qq < 4; ++qq) {
    const int p = g * 4 + qq;
    float c, sn;
    if (p == 0) {
      float rr = (float)s * (1.0f / 512.0f);
      c = cosf(rr); sn = sinf(rr);
    } else {
      // theta = 10000^(-2p)/512; for p>=1, r <= 4e-8 -> cosf(r)==1.0f, sinf(r)==r (fp32-exact)
      float theta = exp2f(-26.5754247590989f * (float)p) * (1.0f / 512.0f);
      sn = (float)s * theta; c = 1.0f;
    }
    float g0 = bfu2f(vr.u[2 * qq]), g1 = bfu2f(vr.u[2 * qq + 1]);
    float c0 = bfu2f(vc.u[2 * qq]), c1 = bfu2f(vc.u[2 * qq + 1]);
    op[qq] = packbf(c0 + g0 * c - g1 * sn, c1 + g1 * c + g0 * sn);
  }
  *(uint4*)&out[(size_t)row * DMODEL + (size_t)g * 8] = o;
}

// ---------------------------------------------------------------- attention v5
// grid (32 bh, 32 qt) [bh on x -> XCD-pinned heads]. 4 waves x 16 q-rows.
// K/V LDS dbuf (XOR-swizzled). Raw v_exp_f32, hoisted LDS addressing, defer-max.
__global__ __launch_bounds__(256) void attn_kernel(
    const bf16* __restrict__ Qn, const bf16* __restrict__ Kn,
    const bf16* __restrict__ VT, bf16* __restrict__ AO) {
  const int bh = blockIdx.x, qt = blockIdx.y;   // bh%8 == XCD -> K/V stays in one L2
  const int b = bh >> 4, h = bh & 15;
  const int tid = threadIdx.x, lane = tid & 63, w = tid >> 6;
  const int q0 = qt * 64 + w * 16;
  const int l15 = lane & 15, lg = lane >> 4;
  const float SC2 = 0.044736075f;    // (1/sqrt(1040)) * log2(e)
  const float THR = 11.5415603f;     // 8 * log2(e)

  __shared__ bf16 ldsK[2][64 * 64];  // 16 KB
  __shared__ bf16 ldsV[2][64 * 64];  // 16 KB
  __shared__ bf16 ldsP[4][16 * 64];  // 8 KB, per-wave

  const bf16* Kg = Kn + (size_t)(b * Ss) * DMODEL + h * 64;
  const bf16* Vg = VT + (size_t)(h * 64) * NTOK + b * Ss;

  // ---- staging pointers (advance by constant stride per tile)
  const int r0 = tid >> 3;
  const int srcb = ((tid & 7) * 16) ^ ((r0 & 7) << 4);
  const char* kS0 = (const char*)(Kg + (size_t)r0 * DMODEL) + srcb;
  const char* kS1 = (const char*)(Kg + (size_t)(32 + r0) * DMODEL) + srcb;
  const char* vS0 = (const char*)(Vg + (size_t)r0 * NTOK) + srcb;
  const char* vS1 = (const char*)(Vg + (size_t)(32 + r0) * NTOK) + srcb;
  const ptrdiff_t kAdv = (ptrdiff_t)64 * DMODEL * 2;   // 64 kv-rows
  const ptrdiff_t vAdv = 128;                           // 64 tokens * 2B

  bf16* kd0_b0 = &ldsK[0][w * 512]; bf16* kd1_b0 = &ldsK[0][2048 + w * 512];
  bf16* kd0_b1 = &ldsK[1][w * 512]; bf16* kd1_b1 = &ldsK[1][2048 + w * 512];
  bf16* vd0_b0 = &ldsV[0][w * 512]; bf16* vd1_b0 = &ldsV[0][2048 + w * 512];
  bf16* vd0_b1 = &ldsV[1][w * 512]; bf16* vd1_b1 = &ldsV[1][2048 + w * 512];

  auto stageTo = [&](bf16* kd0, bf16* kd1, bf16* vd0, bf16* vd1) {
    async_load16((const bf16*)kS0, kd0);
    async_load16((const bf16*)kS1, kd1);
    async_load16((const bf16*)vS0, vd0);
    async_load16((const bf16*)vS1, vd1);
    kS0 += kAdv; kS1 += kAdv; vS0 += vAdv; vS1 += vAdv;
  };

  // ---- hoisted LDS read bases (per buffer; per-read offset is an immediate)
  const int kswz = (l15 & 7) << 4;
  const int xA = (lg * 16) ^ kswz;
  const int xB = (64 + lg * 16) ^ kswz;
  const char* krA0 = (const char*)&ldsK[0][0] + l15 * 128 + xA;
  const char* krB0 = (const char*)&ldsK[0][0] + l15 * 128 + xB;
  const char* krA1 = (const char*)&ldsK[1][0] + l15 * 128 + xA;
  const char* krB1 = (const char*)&ldsK[1][0] + l15 * 128 + xB;
  const char* vrA0 = (const char*)&ldsV[0][0] + l15 * 128 + xA;
  const char* vrB0 = (const char*)&ldsV[0][0] + l15 * 128 + xB;
  const char* vrA1 = (const char*)&ldsV[1][0] + l15 * 128 + xA;
  const char* vrB1 = (const char*)&ldsV[1][0] + l15 * 128 + xB;

  // ---- P pointers (wave-private, loop-invariant)
  char* Pw = (char*)&ldsP[w][0];
  char* pwr[4];
#pragma unroll
  for (int j = 0; j < 4; ++j) {
    const int chunk = (j * 2 + (lg >> 1)) ^ (l15 & 7);
    pwr[j] = Pw + l15 * 128 + chunk * 16 + (lg & 1) * 8;
  }
  const char* paA = Pw + l15 * 128 + xA;
  const char* paB = Pw + l15 * 128 + xB;

  // ---- Q B-frag: Q[q0 + l15][d = kg*32 + lg*8 + e]
  const bf16* Qbase = Qn + (size_t)(b * Ss + q0 + l15) * DMODEL + h * 64;
  bf16x8 bq0 = *(const bf16x8*)&Qbase[lg * 8];
  bf16x8 bq1 = *(const bf16x8*)&Qbase[32 + lg * 8];

  float m = 0.0f, l = 0.0f;         // m=0: defer-max branch is cold on sane logits
  f32x4 accO[4] = {};

  auto body = [&](const char* krA, const char* krB, const char* vrA, const char* vrB) {
    // S^T: sa[j] lane holds raw dot S[k = j*16 + lg*4 + r][q = q0 + l15]
    f32x4 sa[4] = {};
#pragma unroll
    for (int j = 0; j < 4; ++j) {
      bf16x8 ak0 = *(const bf16x8*)(krA + j * 2048);
      bf16x8 ak1 = *(const bf16x8*)(krB + j * 2048);
      sa[j] = __builtin_amdgcn_mfma_f32_16x16x32_bf16(ak0, bq0, sa[j], 0, 0, 0);
      sa[j] = __builtin_amdgcn_mfma_f32_16x16x32_bf16(ak1, bq1, sa[j], 0, 0, 0);
    }
    // defer-max safety check (per-lane max; cold branch does the full reduce)
    float pmaxr = -3.0e38f;
#pragma unroll
    for (int j = 0; j < 4; ++j)
#pragma unroll
      for (int r = 0; r < 4; ++r) pmaxr = fmaxf(pmaxr, sa[j][r]);
    if (__any(fmaf(pmaxr, SC2, -m) > THR)) {
      float px = fmaxf(pmaxr, __shfl_xor(pmaxr, 16, 64));
      px = fmaxf(px, __shfl_xor(px, 32, 64));
      float mnew = fmaxf(m, px * SC2);
      float corr = __builtin_amdgcn_exp2f(m - mnew);
      m = mnew; l *= corr;
      float cr[4];
#pragma unroll
      for (int r = 0; r < 4; ++r) cr[r] = __shfl(corr, lg * 4 + r, 64);
#pragma unroll
      for (int dj = 0; dj < 4; ++dj)
#pragma unroll
        for (int r = 0; r < 4; ++r) accO[dj][r] *= cr[r];
    }
    // p = 2^(sa*SC2 - m), row-sum
    float p[4][4];
    float ts0 = 0.f, ts1 = 0.f;
#pragma unroll
    for (int j = 0; j < 4; ++j) {
#pragma unroll
      for (int r = 0; r < 4; ++r)
        p[j][r] = __builtin_amdgcn_exp2f(fmaf(sa[j][r], SC2, -m));
      ts0 += p[j][0] + p[j][2];
      ts1 += p[j][1] + p[j][3];
    }
    float ts = ts0 + ts1;
    ts += __shfl_xor(ts, 16, 64);
    ts += __shfl_xor(ts, 32, 64);
    l += ts;
    // write P (wave-private, swizzled, precomputed addrs)
#pragma unroll
    for (int j = 0; j < 4; ++j) {
      uint2 pw;
      pw.x = packbf(p[j][0], p[j][1]);
      pw.y = packbf(p[j][2], p[j][3]);
      *(uint2*)pwr[j] = pw;
    }
    // O += P V
    bf16x8 pa0 = *(const bf16x8*)paA;
    bf16x8 pa1 = *(const bf16x8*)paB;
#pragma unroll
    for (int dj = 0; dj < 4; ++dj) {
      bf16x8 bv0 = *(const bf16x8*)(vrA + dj * 2048);
      bf16x8 bv1 = *(const bf16x8*)(vrB + dj * 2048);
      accO[dj] = __builtin_amdgcn_mfma_f32_16x16x32_bf16(pa0, bv0, accO[dj], 0, 0, 0);
      accO[dj] = __builtin_amdgcn_mfma_f32_16x16x32_bf16(pa1, bv1, accO[dj], 0, 0, 0);
    }
  };

  stageTo(kd0_b0, kd1_b0, vd0_b0, vd1_b0);          // tile 0 -> buf0
  for (int tt = 0; tt < 16; ++tt) {
    __syncthreads();                                 // buf0 tile ready; buf1 free
    stageTo(kd0_b1, kd1_b1, vd0_b1, vd1_b1);         // tile 2tt+1 -> buf1
    body(krA0, krB0, vrA0, vrB0);                    // compute tile 2tt
    __syncthreads();                                 // buf1 ready; buf0 free
    if (tt < 15) stageTo(kd0_b0, kd1_b0, vd0_b0, vd1_b0);  // tile 2tt+2 -> buf0
    body(krA1, krB1, vrA1, vrB1);                    // compute tile 2tt+1
  }

  // ---- epilogue: O[q0 + lg*4 + r][dj*16 + l15]
  float linv[4];
#pragma unroll
  for (int r = 0; r < 4; ++r) linv[r] = 1.0f / __shfl(l, lg * 4 + r, 64);
#pragma unroll
  for (int dj = 0; dj < 4; ++dj)
#pragma unroll
    for (int r = 0; r < 4; ++r)
      AO[(size_t)(b * Ss + q0 + lg * 4 + r) * DMODEL + h * 64 + dj * 16 + l15] =
          f2bf(accO[dj][r] * linv[r]);
}

// ---------------------------------------------------------------- launch
extern "C" void kernel_launch(void* const* d_in, const int* in_sizes, int n_in,
                              void* d_out, int out_size, void* d_ws, size_t ws_size,
                              hipStream_t stream) {
  const float* x      = (const float*)d_in[0];
  const float* Wdq    = (const float*)d_in[1];  const float* Wdq_b  = (const float*)d_in[2];
  const float* Wuq    = (const float*)d_in[3];  const float* Wuq_b  = (const float*)d_in[4];
  const float* Wqr    = (const float*)d_in[5];  const float* Wqr_b  = (const float*)d_in[6];
  const float* Wkr    = (const float*)d_in[7];  const float* Wkr_b  = (const float*)d_in[8];
  const float* Wdkv   = (const float*)d_in[9];  const float* Wdkv_b = (const float*)d_in[10];
  const float* Wuk    = (const float*)d_in[11]; const float* Wuk_b  = (const float*)d_in[12];
  const float* Wuv    = (const float*)d_in[13]; const float* Wuv_b  = (const float*)d_in[14];
  const float* Wo     = (const float*)d_in[15]; const float* Wo_b   = (const float*)d_in[16];

  // ---- workspace (~42 MB) ----
  char* ws = (char*)d_ws;
  size_t off = 0;
  bf16* WdqT   = (bf16*)(ws + off); off += (size_t)512  * 1024 * 2;
  bf16* WdkvT  = (bf16*)(ws + off); off += (size_t)512  * 1024 * 2;
  bf16* WuqT   = (bf16*)(ws + off); off += (size_t)1024 * 512  * 2;
  bf16* WqrT   = (bf16*)(ws + off); off += (size_t)1024 * 512  * 2;
  bf16* WukT   = (bf16*)(ws + off); off += (size_t)1024 * 512  * 2;
  bf16* WuvT   = (bf16*)(ws + off); off += (size_t)1024 * 512  * 2;
  bf16* WkrT   = (bf16*)(ws + off); off += (size_t)1024 * 1024 * 2;
  bf16* WoT    = (bf16*)(ws + off); off += (size_t)1024 * 1024 * 2;
  bf16* x_bf   = (bf16*)(ws + off); off += (size_t)NTOK * 1024 * 2;   // reused as Gupk
  bf16* ct     = (bf16*)(ws + off); off += (size_t)NTOK * 1024 * 2;   // [ct_q | ct_kv]
  bf16* Ga     = (bf16*)(ws + off); off += (size_t)NTOK * 1024 * 2;   // upQc, later AO
  bf16* VTr    = (bf16*)(ws + off); off += (size_t)NTOK * 1024 * 2;
  bf16* Gupk   = x_bf;                                 // x_bf dead after batch A
  bf16* Qn     = (bf16*)d_out;                         // dead before final GEMM
  bf16* Kn     = (bf16*)d_out + (size_t)NTOK * DMODEL;
  bf16* AO     = Ga;
  (void)ws_size; (void)in_sizes; (void)n_in; (void)out_size;

  TransPack tp = {{
    { Wdq,  WdqT,  1024, 512,  0    },
    { Wdkv, WdkvT, 1024, 512,  128  },
    { Wuq,  WuqT,  512,  1024, 256  },
    { Wqr,  WqrT,  512,  1024, 384  },
    { Wuk,  WukT,  512,  1024, 512  },
    { Wuv,  WuvT,  512,  1024, 640  },
    { Wkr,  WkrT,  1024, 1024, 768  },
    { Wo,   WoT,   1024, 1024, 1024 },
  }};
  transpose8_kernel<<<1280, 256, 0, stream>>>(tp);
  convert_kernel<<<(NTOK * DMODEL / 4 + 255) / 256, 256, 0, stream>>>(x, x_bf, NTOK * DMODEL / 4);

  // ---- batch A (512 blocks): down = x@[Wdq|Wdkv] -> ct ; Kr = x@Wkr -> Kn region ----
  GemmBatch ba = {{
    { x_bf, WdqT, Wdq_b, Wdkv_b, ct, 1024, 1024, 1024, 1024, 512,     8, 0,       0 },
    { x_bf, WkrT, Wkr_b, Wkr_b,  Kn, 1024, 1024, 1024, 1024, INT_MAX, 8, 256,     0 },
    { 0, 0, 0, 0, 0, 0, 0, 0, 0, 0, 1, INT_MAX, 0 },
    { 0, 0, 0, 0, 0, 0, 0, 0, 0, 0, 1, INT_MAX, 0 },
  }};
  gemm_batch_kernel<<<512, 256, 0, stream>>>(ba);

  // ---- batch B (1024 blocks): upQc->Ga ; upQr->Qn ; upK->Gupk ; V^T->VTr ----
  GemmBatch bb = {{
    { ct,       WuqT,     Wuq_b, Wuq_b, Ga,   1024, 512,  1024, 512, INT_MAX, 8,  0,   0 },
    { ct,       WqrT,     Wqr_b, Wqr_b, Qn,   1024, 512,  1024, 512, INT_MAX, 8,  256, 0 },
    { ct + 512, WukT,     Wuk_b, Wuk_b, Gupk, 1024, 512,  1024, 512, INT_MAX, 8,  512, 0 },
    { WuvT,     ct + 512, Wuv_b, Wuv_b, VTr,  512,  1024, NTOK, 512, INT_MAX, 32, 768, 1 },
  }};
  gemm_batch_kernel<<<1024, 256, 0, stream>>>(bb);

  // combines (in place on the rope operand)
  combine_rope_kernel<<<NTOK * 128 / 256, 256, 0, stream>>>(Ga, 1024, Qn, 1024, Qn);
  combine_rope_kernel<<<NTOK * 128 / 256, 256, 0, stream>>>(Gupk, 1024, Kn, 1024, Kn);

  // attention (bh on x for XCD-L2 pinning)
  attn_kernel<<<dim3(32, 32), 256, 0, stream>>>(Qn, Kn, VTr, AO);

  // output projection (fp32 out)
  gemm_kernel_f32<<<dim3(8, 32), 256, 0, stream>>>(
      AO, 1024, WoT, 1024, Wo_b, (float*)d_out, 1024, 1024);
}